// Round 2
// baseline (3399.069 us; speedup 1.0000x reference)
//
#include <hip/hip_runtime.h>
#include <hip/hip_bf16.h>
#include <cstdint>

// Problem constants (from reference)
#define IN_DIM 128
#define CCH 32
#define H_STD 3
#define OUT_STD 96      // H_STD*C
#define OUT_REP 32
#define OUT_ALL 128     // 96 + 32
#define XLR_LD 256      // [xl_s(96) | xr_s(96) | xl_r(32) | xr_r(32)]
#define NEG_SLOPE 0.2f

// ---------------------------------------------------------------------------
// Mask dtype detection: harness may push the JAX bool as uint8 / int32 / f32.
// Inspect first <=4096 bytes: any byte >1  -> float32 (bytes 0x80/0x3F appear)
//                             nonzero only at pos%4==0 -> int32 (LE 0/1 words)
//                             else -> uint8
// ---------------------------------------------------------------------------
__global__ void mask_detect(const unsigned char* __restrict__ m, int* __restrict__ flag, int nbytes)
{
    if (threadIdx.x == 0 && blockIdx.x == 0) {
        int anyGT1 = 0, any123 = 0;
        for (int i = 0; i < nbytes; ++i) {
            unsigned char b = m[i];
            if (b > 1) anyGT1 = 1;
            if ((i & 3) && b) any123 = 1;
        }
        *flag = anyGT1 ? 2 : (any123 ? 0 : 1);
    }
}

__global__ __launch_bounds__(256) void mask_convert(
    const void* __restrict__ m, const int* __restrict__ flag,
    unsigned char* __restrict__ mk8, int E)
{
    int e = blockIdx.x * 256 + threadIdx.x;
    if (e >= E) return;
    int fl = *flag;
    bool v;
    if (fl == 1)      v = ((const int*)m)[e] != 0;
    else if (fl == 2) v = ((const float*)m)[e] != 0.f;
    else              v = ((const unsigned char*)m)[e] != 0;
    mk8[e] = v ? 1 : 0;
}

// ---------------------------------------------------------------------------
// Edge encoder MLP 7->32->16 (+ dst-degree histogram, + sums for means)
// sums layout: [0..15] sum(ea), [16..31] sum(ea*mask), [32] sum(mask)
// ---------------------------------------------------------------------------
__global__ __launch_bounds__(256) void edge_enc(
    const float* __restrict__ raw, const int* __restrict__ ei,
    const unsigned char* __restrict__ mask,
    const float* __restrict__ w1, const float* __restrict__ b1,
    const float* __restrict__ w2, const float* __restrict__ b2,
    float* __restrict__ ea, int* __restrict__ deg, float* __restrict__ sums, int E)
{
    __shared__ float sW1[7 * 32];
    __shared__ float sB1[32];
    __shared__ float sW2[32 * 16];
    __shared__ float sB2[16];
    int t = threadIdx.x;
    if (t < 224) sW1[t] = w1[t];
    if (t < 32)  sB1[t] = b1[t];
    for (int i = t; i < 512; i += 256) sW2[i] = w2[i];
    if (t < 16)  sB2[t] = b2[t];
    __syncthreads();

    int e = blockIdx.x * 256 + t;
    float o[16];
    float mk = 0.f;
    if (e < E) {
        float r[7];
#pragma unroll
        for (int k = 0; k < 7; ++k) r[k] = raw[(size_t)e * 7 + k];
#pragma unroll
        for (int j = 0; j < 16; ++j) o[j] = sB2[j];
#pragma unroll
        for (int jh = 0; jh < 32; ++jh) {
            float hv = sB1[jh];
#pragma unroll
            for (int k = 0; k < 7; ++k) hv += r[k] * sW1[k * 32 + jh];
            hv = hv > 0.f ? hv : 0.f;
#pragma unroll
            for (int j = 0; j < 16; ++j) o[j] += hv * sW2[jh * 16 + j];
        }
        float4* dst = (float4*)(ea + (size_t)e * 16);
        dst[0] = make_float4(o[0], o[1], o[2], o[3]);
        dst[1] = make_float4(o[4], o[5], o[6], o[7]);
        dst[2] = make_float4(o[8], o[9], o[10], o[11]);
        dst[3] = make_float4(o[12], o[13], o[14], o[15]);
        atomicAdd(&deg[ei[E + e]], 1);
        mk = mask[e] ? 1.f : 0.f;
    } else {
#pragma unroll
        for (int j = 0; j < 16; ++j) o[j] = 0.f;
    }

    // wave-level reductions, one atomic per wave per value
#pragma unroll
    for (int j = 0; j < 16; ++j) {
        float v = o[j];
        float vm = o[j] * mk;
#pragma unroll
        for (int off = 32; off; off >>= 1) {
            v  += __shfl_xor(v, off, 64);
            vm += __shfl_xor(vm, off, 64);
        }
        if ((t & 63) == 0) { atomicAdd(&sums[j], v); atomicAdd(&sums[16 + j], vm); }
    }
    float cm = mk;
#pragma unroll
    for (int off = 32; off; off >>= 1) cm += __shfl_xor(cm, off, 64);
    if ((t & 63) == 0) atomicAdd(&sums[32], cm);
}

// ---------------------------------------------------------------------------
// CSR build: scan of degree histogram (3 kernels) + fill
// ---------------------------------------------------------------------------
__global__ __launch_bounds__(256) void scan1(const int* __restrict__ deg, int* __restrict__ part, int n)
{
    __shared__ int sm[256];
    int i = blockIdx.x * 256 + threadIdx.x;
    sm[threadIdx.x] = (i < n) ? deg[i] : 0;
    __syncthreads();
    for (int s = 128; s; s >>= 1) {
        if (threadIdx.x < s) sm[threadIdx.x] += sm[threadIdx.x + s];
        __syncthreads();
    }
    if (threadIdx.x == 0) part[blockIdx.x] = sm[0];
}

__global__ __launch_bounds__(256) void scan2(int* __restrict__ part, int nb)
{
    __shared__ int sm[256];
    int t = threadIdx.x;
    int v = (t < nb) ? part[t] : 0;
    sm[t] = v;
    __syncthreads();
    for (int o = 1; o < 256; o <<= 1) {
        int add = (t >= o) ? sm[t - o] : 0;
        __syncthreads();
        sm[t] += add;
        __syncthreads();
    }
    if (t < nb) part[t] = sm[t] - v;  // exclusive
}

__global__ __launch_bounds__(256) void scan3(const int* __restrict__ deg, const int* __restrict__ part,
                                             int* __restrict__ row_ofs, int* __restrict__ cursor,
                                             int n, int E)
{
    __shared__ int sm[256];
    int t = threadIdx.x;
    int i = blockIdx.x * 256 + t;
    int v = (i < n) ? deg[i] : 0;
    sm[t] = v;
    __syncthreads();
    for (int o = 1; o < 256; o <<= 1) {
        int add = (t >= o) ? sm[t - o] : 0;
        __syncthreads();
        sm[t] += add;
        __syncthreads();
    }
    int excl = sm[t] - v + part[blockIdx.x];
    if (i < n) { row_ofs[i] = excl; cursor[i] = excl; }
    if (blockIdx.x == 0 && t == 0) row_ofs[n] = E;
}

__global__ __launch_bounds__(256) void csr_fill(const int* __restrict__ ei, int* __restrict__ cursor,
                                                int* __restrict__ csr_eid, int E)
{
    int e = blockIdx.x * 256 + threadIdx.x;
    if (e < E) {
        int d = ei[E + e];
        int slot = atomicAdd(&cursor[d], 1);
        csr_eid[slot] = e;
    }
}

// ---------------------------------------------------------------------------
// Pack the 4 node-transform weight matrices into Wp[128][256] + biasp[256]
// cols: [0,96) wl_s | [96,192) wr_s | [192,224) wl_r | [224,256) wr_r
// ---------------------------------------------------------------------------
__global__ __launch_bounds__(256) void pack_w(
    const float* __restrict__ wls, const float* __restrict__ wrs,
    const float* __restrict__ wlr, const float* __restrict__ wrr,
    const float* __restrict__ bls, const float* __restrict__ brs,
    const float* __restrict__ blr, const float* __restrict__ brr,
    float* __restrict__ Wp, float* __restrict__ biasp)
{
    int idx = blockIdx.x * 256 + threadIdx.x;
    if (idx < IN_DIM * XLR_LD) {
        int k = idx >> 8, j = idx & 255;
        float v;
        if (j < 96)       v = wls[k * 96 + j];
        else if (j < 192) v = wrs[k * 96 + (j - 96)];
        else if (j < 224) v = wlr[k * 32 + (j - 192)];
        else              v = wrr[k * 32 + (j - 224)];
        Wp[idx] = v;
    }
    if (idx < 256) {
        float b;
        if (idx < 96)       b = bls[idx];
        else if (idx < 192) b = brs[idx - 96];
        else if (idx < 224) b = blr[idx - 192];
        else                b = brr[idx - 224];
        biasp[idx] = b;
    }
}

// ---------------------------------------------------------------------------
// Node transforms: XLR = x @ Wp + biasp   (f32 tiled GEMM, M=N nodes, K=128, N'=256)
// ---------------------------------------------------------------------------
#define GM_BM 64
#define GM_BK 16
__global__ __launch_bounds__(256) void node_gemm(
    const float* __restrict__ x, const float* __restrict__ Wp,
    const float* __restrict__ biasp, float* __restrict__ XLR, int n)
{
    __shared__ __align__(16) float As[GM_BK][GM_BM];
    __shared__ __align__(16) float Bs[GM_BK][XLR_LD];
    int tid = threadIdx.x;
    int tm = tid >> 5;   // 0..7
    int tn = tid & 31;   // 0..31
    int m0 = blockIdx.x * GM_BM;
    float acc[8][8] = {{0.f}};

    for (int k0 = 0; k0 < IN_DIM; k0 += GM_BK) {
        {   // stage A (64 rows x 16 k), transposed into As[k][m]
            int r = tid >> 2, c0 = (tid & 3) * 4;
            float4 av = make_float4(0.f, 0.f, 0.f, 0.f);
            if (m0 + r < n) av = *(const float4*)(x + (size_t)(m0 + r) * IN_DIM + k0 + c0);
            As[c0 + 0][r] = av.x; As[c0 + 1][r] = av.y;
            As[c0 + 2][r] = av.z; As[c0 + 3][r] = av.w;
        }
        {   // stage B (16 k x 256 cols)
            int rb = tid >> 4, cb0 = (tid & 15) * 16;
            const float4* src = (const float4*)(Wp + (size_t)(k0 + rb) * XLR_LD + cb0);
            float4 b0 = src[0], b1 = src[1], b2 = src[2], b3 = src[3];
            *(float4*)&Bs[rb][cb0 + 0]  = b0; *(float4*)&Bs[rb][cb0 + 4]  = b1;
            *(float4*)&Bs[rb][cb0 + 8]  = b2; *(float4*)&Bs[rb][cb0 + 12] = b3;
        }
        __syncthreads();
#pragma unroll
        for (int k = 0; k < GM_BK; ++k) {
            float a[8], b[8];
            *(float4*)&a[0] = *(const float4*)&As[k][tm * 8];
            *(float4*)&a[4] = *(const float4*)&As[k][tm * 8 + 4];
#pragma unroll
            for (int j = 0; j < 8; ++j) b[j] = Bs[k][tn + 32 * j];
#pragma unroll
            for (int i = 0; i < 8; ++i)
#pragma unroll
                for (int j = 0; j < 8; ++j) acc[i][j] += a[i] * b[j];
        }
        __syncthreads();
    }

#pragma unroll
    for (int i = 0; i < 8; ++i) {
        int row = m0 + tm * 8 + i;
        if (row < n) {
#pragma unroll
            for (int j = 0; j < 8; ++j) {
                int col = tn + 32 * j;
                XLR[(size_t)row * XLR_LD + col] = acc[i][j] + biasp[col];
            }
        }
    }
}

// ---------------------------------------------------------------------------
// Self-loop edge transform: ef_loop[0..95] = mean(ea) @ we_s ; [96..127] = masked mean @ we_r
// ---------------------------------------------------------------------------
__global__ __launch_bounds__(128) void finalize_means(
    const float* __restrict__ sums, const float* __restrict__ we_s,
    const float* __restrict__ we_r, float* __restrict__ ef_loop, int E)
{
    int f = threadIdx.x;
    float v = 0.f;
    if (f < OUT_STD) {
        float inv = 1.f / (float)E;
#pragma unroll
        for (int k = 0; k < 16; ++k) v += sums[k] * inv * we_s[k * OUT_STD + f];
    } else {
        float cnt = sums[32];
        cnt = cnt < 1.f ? 1.f : cnt;
        float inv = 1.f / cnt;
        int c = f - OUT_STD;
#pragma unroll
        for (int k = 0; k < 16; ++k) v += sums[16 + k] * inv * we_r[k * OUT_REP + c];
    }
    ef_loop[f] = v;
}

// ---------------------------------------------------------------------------
// Main fused GATv2: one 128-thread block per node, lane = output feature
// lanes 0..95 = std conv (3 heads x 32), lanes 96..127 = rep conv (1 head)
// ---------------------------------------------------------------------------
__global__ __launch_bounds__(128) void gat_main(
    const float* __restrict__ XLR, const float* __restrict__ ea,
    const int* __restrict__ csr_eid, const int* __restrict__ row_ofs,
    const int* __restrict__ ei, const unsigned char* __restrict__ mask,
    const float* __restrict__ we_s, const float* __restrict__ we_r,
    const float* __restrict__ att_s, const float* __restrict__ att_r,
    const float* __restrict__ bias_s, const float* __restrict__ bias_r,
    const float* __restrict__ ef_loop, float* __restrict__ out, int n)
{
    int node = blockIdx.x;
    int f = threadIdx.x;
    bool is_std = f < OUT_STD;
    int c = f & 31;

    int xl_off = is_std ? f : (96 + f);          // rep: 192 + (f-96)
    int xr_off = is_std ? (96 + f) : (128 + f);  // rep: 224 + (f-96)

    float wecol[16];
    if (is_std) {
#pragma unroll
        for (int k = 0; k < 16; ++k) wecol[k] = we_s[k * OUT_STD + f];
    } else {
#pragma unroll
        for (int k = 0; k < 16; ++k) wecol[k] = we_r[k * OUT_REP + (f - OUT_STD)];
    }
    float attv  = is_std ? att_s[(f >> 5) * 32 + c] : att_r[c];
    float biasv = is_std ? bias_s[f] : bias_r[f - OUT_STD];

    const float* xrow = XLR + (size_t)node * XLR_LD;
    float xr_n = xrow[xr_off];
    float xl_n = xrow[xl_off];

    // self-loop: init online softmax state
    float msg = xl_n + xr_n + ef_loop[f];
    float s = (msg > 0.f ? msg : NEG_SLOPE * msg) * attv;
#pragma unroll
    for (int o = 16; o; o >>= 1) s += __shfl_xor(s, o, 32);
    float m = s, denom = 1.f, acc = xl_n;

    int p0 = row_ofs[node], p1 = row_ofs[node + 1];
    for (int p = p0; p < p1; ++p) {
        int e = csr_eid[p];
        int src = ei[e];
        bool act = is_std || (mask[e] != 0);

        const float4* eap = (const float4*)(ea + (size_t)e * 16);
        float4 e0 = eap[0], e1 = eap[1], e2 = eap[2], e3 = eap[3];
        float ef = e0.x * wecol[0] + e0.y * wecol[1] + e0.z * wecol[2] + e0.w * wecol[3]
                 + e1.x * wecol[4] + e1.y * wecol[5] + e1.z * wecol[6] + e1.w * wecol[7]
                 + e2.x * wecol[8] + e2.y * wecol[9] + e2.z * wecol[10] + e2.w * wecol[11]
                 + e3.x * wecol[12] + e3.y * wecol[13] + e3.z * wecol[14] + e3.w * wecol[15];

        float xls = XLR[(size_t)src * XLR_LD + xl_off];
        float mg = xls + xr_n + ef;
        float sc = (mg > 0.f ? mg : NEG_SLOPE * mg) * attv;
#pragma unroll
        for (int o = 16; o; o >>= 1) sc += __shfl_xor(sc, o, 32);

        if (act) {  // uniform within each 32-lane head group
            if (sc > m) {
                float r = __expf(m - sc);
                denom = denom * r + 1.f;
                acc = acc * r + xls;
                m = sc;
            } else {
                float p2 = __expf(sc - m);
                denom += p2;
                acc += p2 * xls;
            }
        }
    }
    out[(size_t)node * OUT_ALL + f] = acc / denom + biasv;
}

// ---------------------------------------------------------------------------
extern "C" void kernel_launch(void* const* d_in, const int* in_sizes, int n_in,
                              void* d_out, int out_size, void* d_ws, size_t ws_size,
                              hipStream_t stream)
{
    const float* x    = (const float*)d_in[0];
    const float* raw  = (const float*)d_in[1];
    const int*   ei   = (const int*)d_in[2];
    const void*  mask_raw = d_in[3];
    const float* ee_w1 = (const float*)d_in[4];
    const float* ee_b1 = (const float*)d_in[5];
    const float* ee_w2 = (const float*)d_in[6];
    const float* ee_b2 = (const float*)d_in[7];
    const float* wl_s = (const float*)d_in[8];
    const float* bl_s = (const float*)d_in[9];
    const float* wr_s = (const float*)d_in[10];
    const float* br_s = (const float*)d_in[11];
    const float* we_s = (const float*)d_in[12];
    const float* att_s = (const float*)d_in[13];
    const float* bias_s = (const float*)d_in[14];
    const float* wl_r = (const float*)d_in[15];
    const float* bl_r = (const float*)d_in[16];
    const float* wr_r = (const float*)d_in[17];
    const float* br_r = (const float*)d_in[18];
    const float* we_r = (const float*)d_in[19];
    const float* att_r = (const float*)d_in[20];
    const float* bias_r = (const float*)d_in[21];

    const int N = in_sizes[0] / IN_DIM;
    const int E = in_sizes[1] / 7;

    // workspace carve-up (all offsets 256B-aligned)
    char* w = (char*)d_ws;
    size_t off = 0;
    auto carve = [&](size_t bytes) {
        void* p = w + off;
        off = (off + bytes + 255) & ~(size_t)255;
        return p;
    };
    float* XLR     = (float*)carve((size_t)N * XLR_LD * 4);
    float* ea      = (float*)carve((size_t)E * 16 * 4);
    int*   csr_eid = (int*)carve((size_t)E * 4);
    unsigned char* mk8 = (unsigned char*)carve((size_t)E);
    int*   row_ofs = (int*)carve((size_t)(N + 1) * 4);
    int*   cursor  = (int*)carve((size_t)N * 4);
    int*   deg     = (int*)carve((size_t)N * 4);
    int*   part    = (int*)carve(1024);
    float* sums    = (float*)carve(256);
    float* ef_loop = (float*)carve(512);
    float* Wp      = (float*)carve((size_t)IN_DIM * XLR_LD * 4);
    float* biasp   = (float*)carve(1024);
    int*   mflag   = (int*)carve(256);
    (void)ws_size; (void)n_in; (void)out_size;

    hipMemsetAsync(deg, 0, (size_t)N * 4, stream);
    hipMemsetAsync(sums, 0, 256, stream);

    int ebl = (E + 255) / 256;
    int nbl = (N + 255) / 256;

    int nprobe = E < 4096 ? E : 4096;
    mask_detect<<<1, 64, 0, stream>>>((const unsigned char*)mask_raw, mflag, nprobe);
    mask_convert<<<ebl, 256, 0, stream>>>(mask_raw, mflag, mk8, E);

    edge_enc<<<ebl, 256, 0, stream>>>(raw, ei, mk8, ee_w1, ee_b1, ee_w2, ee_b2, ea, deg, sums, E);
    scan1<<<nbl, 256, 0, stream>>>(deg, part, N);
    scan2<<<1, 256, 0, stream>>>(part, nbl);
    scan3<<<nbl, 256, 0, stream>>>(deg, part, row_ofs, cursor, N, E);
    csr_fill<<<ebl, 256, 0, stream>>>(ei, cursor, csr_eid, E);
    pack_w<<<(IN_DIM * XLR_LD + 255) / 256, 256, 0, stream>>>(
        wl_s, wr_s, wl_r, wr_r, bl_s, br_s, bl_r, br_r, Wp, biasp);
    node_gemm<<<(N + GM_BM - 1) / GM_BM, 256, 0, stream>>>(x, Wp, biasp, XLR, N);
    finalize_means<<<1, 128, 0, stream>>>(sums, we_s, we_r, ef_loop, E);
    gat_main<<<N, 128, 0, stream>>>(XLR, ea, csr_eid, row_ofs, ei, mk8,
                                    we_s, we_r, att_s, att_r, bias_s, bias_r,
                                    ef_loop, (float*)d_out, N);
}

// Round 3
// 498.428 us; speedup vs baseline: 6.8196x; 6.8196x over previous
//
#include <hip/hip_runtime.h>
#include <hip/hip_bf16.h>
#include <cstdint>

// Problem constants (from reference)
#define IN_DIM 128
#define CCH 32
#define H_STD 3
#define OUT_STD 96      // H_STD*C
#define OUT_REP 32
#define OUT_ALL 128     // 96 + 32
#define XLR_LD 256      // [xl_s(96) | xr_s(96) | xl_r(32) | xr_r(32)]
#define NEG_SLOPE 0.2f
#define EE_BLOCKS 512

// ---------------------------------------------------------------------------
// Mask dtype detection (parallel over 64 lanes).
// any byte >1 -> float32; nonzero only at pos%4==0 -> int32; else uint8
// ---------------------------------------------------------------------------
__global__ void mask_detect(const unsigned char* __restrict__ m, int* __restrict__ flag, int nbytes)
{
    int t = threadIdx.x;
    int anyGT1 = 0, any123 = 0;
    for (int i = t; i < nbytes; i += 64) {
        unsigned char b = m[i];
        if (b > 1) anyGT1 = 1;
        if ((i & 3) && b) any123 = 1;
    }
    anyGT1 = __any(anyGT1);
    any123 = __any(any123);
    if (t == 0) *flag = anyGT1 ? 2 : (any123 ? 0 : 1);
}

__global__ __launch_bounds__(256) void mask_convert(
    const void* __restrict__ m, const int* __restrict__ flag,
    unsigned char* __restrict__ mk8, int E)
{
    int e = blockIdx.x * 256 + threadIdx.x;
    if (e >= E) return;
    int fl = *flag;
    bool v;
    if (fl == 1)      v = ((const int*)m)[e] != 0;
    else if (fl == 2) v = ((const float*)m)[e] != 0.f;
    else              v = ((const unsigned char*)m)[e] != 0;
    mk8[e] = v ? 1 : 0;
}

// ---------------------------------------------------------------------------
// Edge encoder MLP 7->32->16, grid-stride; per-thread register accumulation of
// sums, then wave-shuffle + LDS reduce, ONE atomicAdd per block per value.
// sums layout: [0..15] sum(ea), [16..31] sum(ea*mask), [32] sum(mask)
// ---------------------------------------------------------------------------
__global__ __launch_bounds__(256) void edge_enc(
    const float* __restrict__ raw, const int* __restrict__ ei,
    const unsigned char* __restrict__ mask,
    const float* __restrict__ w1, const float* __restrict__ b1,
    const float* __restrict__ w2, const float* __restrict__ b2,
    float* __restrict__ ea, int* __restrict__ deg, float* __restrict__ sums, int E)
{
    __shared__ float sW1[7 * 32];
    __shared__ float sB1[32];
    __shared__ float sW2[32 * 16];
    __shared__ float sB2[16];
    __shared__ float red[33][4];
    int t = threadIdx.x;
    if (t < 224) sW1[t] = w1[t];
    if (t < 32)  sB1[t] = b1[t];
    for (int i = t; i < 512; i += 256) sW2[i] = w2[i];
    if (t < 16)  sB2[t] = b2[t];
    __syncthreads();

    float accs[16], accm[16], cnt = 0.f;
#pragma unroll
    for (int j = 0; j < 16; ++j) { accs[j] = 0.f; accm[j] = 0.f; }

    for (int e = blockIdx.x * 256 + t; e < E; e += gridDim.x * 256) {
        float r[7];
#pragma unroll
        for (int k = 0; k < 7; ++k) r[k] = raw[(size_t)e * 7 + k];
        float o[16];
#pragma unroll
        for (int j = 0; j < 16; ++j) o[j] = sB2[j];
#pragma unroll
        for (int jh = 0; jh < 32; ++jh) {
            float hv = sB1[jh];
#pragma unroll
            for (int k = 0; k < 7; ++k) hv += r[k] * sW1[k * 32 + jh];
            hv = hv > 0.f ? hv : 0.f;
#pragma unroll
            for (int j = 0; j < 16; ++j) o[j] += hv * sW2[jh * 16 + j];
        }
        float4* dst = (float4*)(ea + (size_t)e * 16);
        dst[0] = make_float4(o[0], o[1], o[2], o[3]);
        dst[1] = make_float4(o[4], o[5], o[6], o[7]);
        dst[2] = make_float4(o[8], o[9], o[10], o[11]);
        dst[3] = make_float4(o[12], o[13], o[14], o[15]);
        atomicAdd(&deg[ei[E + e]], 1);
        float mk = mask[e] ? 1.f : 0.f;
#pragma unroll
        for (int j = 0; j < 16; ++j) { accs[j] += o[j]; accm[j] += o[j] * mk; }
        cnt += mk;
    }

    int wv = t >> 6, ln = t & 63;
#pragma unroll
    for (int j = 0; j < 16; ++j) {
        float v = accs[j], vm = accm[j];
#pragma unroll
        for (int off = 32; off; off >>= 1) {
            v  += __shfl_xor(v, off, 64);
            vm += __shfl_xor(vm, off, 64);
        }
        if (ln == 0) { red[j][wv] = v; red[16 + j][wv] = vm; }
    }
    {
        float c = cnt;
#pragma unroll
        for (int off = 32; off; off >>= 1) c += __shfl_xor(c, off, 64);
        if (ln == 0) red[32][wv] = c;
    }
    __syncthreads();
    if (t < 33) {
        float v = red[t][0] + red[t][1] + red[t][2] + red[t][3];
        atomicAdd(&sums[t], v);
    }
}

// ---------------------------------------------------------------------------
// CSR build: scan of degree histogram (3 kernels) + fill
// ---------------------------------------------------------------------------
__global__ __launch_bounds__(256) void scan1(const int* __restrict__ deg, int* __restrict__ part, int n)
{
    __shared__ int sm[256];
    int i = blockIdx.x * 256 + threadIdx.x;
    sm[threadIdx.x] = (i < n) ? deg[i] : 0;
    __syncthreads();
    for (int s = 128; s; s >>= 1) {
        if (threadIdx.x < s) sm[threadIdx.x] += sm[threadIdx.x + s];
        __syncthreads();
    }
    if (threadIdx.x == 0) part[blockIdx.x] = sm[0];
}

__global__ __launch_bounds__(256) void scan2(int* __restrict__ part, int nb)
{
    __shared__ int sm[256];
    int t = threadIdx.x;
    int v = (t < nb) ? part[t] : 0;
    sm[t] = v;
    __syncthreads();
    for (int o = 1; o < 256; o <<= 1) {
        int add = (t >= o) ? sm[t - o] : 0;
        __syncthreads();
        sm[t] += add;
        __syncthreads();
    }
    if (t < nb) part[t] = sm[t] - v;  // exclusive
}

__global__ __launch_bounds__(256) void scan3(const int* __restrict__ deg, const int* __restrict__ part,
                                             int* __restrict__ row_ofs, int* __restrict__ cursor,
                                             int n, int E)
{
    __shared__ int sm[256];
    int t = threadIdx.x;
    int i = blockIdx.x * 256 + t;
    int v = (i < n) ? deg[i] : 0;
    sm[t] = v;
    __syncthreads();
    for (int o = 1; o < 256; o <<= 1) {
        int add = (t >= o) ? sm[t - o] : 0;
        __syncthreads();
        sm[t] += add;
        __syncthreads();
    }
    int excl = sm[t] - v + part[blockIdx.x];
    if (i < n) { row_ofs[i] = excl; cursor[i] = excl; }
    if (blockIdx.x == 0 && t == 0) row_ofs[n] = E;
}

__global__ __launch_bounds__(256) void csr_fill(const int* __restrict__ ei, int* __restrict__ cursor,
                                                int* __restrict__ csr_eid, int E)
{
    int e = blockIdx.x * 256 + threadIdx.x;
    if (e < E) {
        int d = ei[E + e];
        int slot = atomicAdd(&cursor[d], 1);
        csr_eid[slot] = e;
    }
}

// ---------------------------------------------------------------------------
// Pack the 4 node-transform weight matrices into Wp[128][256] + biasp[256]
// cols: [0,96) wl_s | [96,192) wr_s | [192,224) wl_r | [224,256) wr_r
// ---------------------------------------------------------------------------
__global__ __launch_bounds__(256) void pack_w(
    const float* __restrict__ wls, const float* __restrict__ wrs,
    const float* __restrict__ wlr, const float* __restrict__ wrr,
    const float* __restrict__ bls, const float* __restrict__ brs,
    const float* __restrict__ blr, const float* __restrict__ brr,
    float* __restrict__ Wp, float* __restrict__ biasp)
{
    int idx = blockIdx.x * 256 + threadIdx.x;
    if (idx < IN_DIM * XLR_LD) {
        int k = idx >> 8, j = idx & 255;
        float v;
        if (j < 96)       v = wls[k * 96 + j];
        else if (j < 192) v = wrs[k * 96 + (j - 96)];
        else if (j < 224) v = wlr[k * 32 + (j - 192)];
        else              v = wrr[k * 32 + (j - 224)];
        Wp[idx] = v;
    }
    if (idx < 256) {
        float b;
        if (idx < 96)       b = bls[idx];
        else if (idx < 192) b = brs[idx - 96];
        else if (idx < 224) b = blr[idx - 192];
        else                b = brr[idx - 224];
        biasp[idx] = b;
    }
}

// ---------------------------------------------------------------------------
// Node transforms: XLR = x @ Wp + biasp   (f32 tiled GEMM, M=N nodes, K=128, N'=256)
// ---------------------------------------------------------------------------
#define GM_BM 64
#define GM_BK 16
__global__ __launch_bounds__(256) void node_gemm(
    const float* __restrict__ x, const float* __restrict__ Wp,
    const float* __restrict__ biasp, float* __restrict__ XLR, int n)
{
    __shared__ __align__(16) float As[GM_BK][GM_BM];
    __shared__ __align__(16) float Bs[GM_BK][XLR_LD];
    int tid = threadIdx.x;
    int tm = tid >> 5;   // 0..7
    int tn = tid & 31;   // 0..31
    int m0 = blockIdx.x * GM_BM;
    float acc[8][8] = {{0.f}};

    for (int k0 = 0; k0 < IN_DIM; k0 += GM_BK) {
        {   // stage A (64 rows x 16 k), transposed into As[k][m]
            int r = tid >> 2, c0 = (tid & 3) * 4;
            float4 av = make_float4(0.f, 0.f, 0.f, 0.f);
            if (m0 + r < n) av = *(const float4*)(x + (size_t)(m0 + r) * IN_DIM + k0 + c0);
            As[c0 + 0][r] = av.x; As[c0 + 1][r] = av.y;
            As[c0 + 2][r] = av.z; As[c0 + 3][r] = av.w;
        }
        {   // stage B (16 k x 256 cols)
            int rb = tid >> 4, cb0 = (tid & 15) * 16;
            const float4* src = (const float4*)(Wp + (size_t)(k0 + rb) * XLR_LD + cb0);
            float4 b0 = src[0], b1 = src[1], b2 = src[2], b3 = src[3];
            *(float4*)&Bs[rb][cb0 + 0]  = b0; *(float4*)&Bs[rb][cb0 + 4]  = b1;
            *(float4*)&Bs[rb][cb0 + 8]  = b2; *(float4*)&Bs[rb][cb0 + 12] = b3;
        }
        __syncthreads();
#pragma unroll
        for (int k = 0; k < GM_BK; ++k) {
            float a[8], b[8];
            *(float4*)&a[0] = *(const float4*)&As[k][tm * 8];
            *(float4*)&a[4] = *(const float4*)&As[k][tm * 8 + 4];
#pragma unroll
            for (int j = 0; j < 8; ++j) b[j] = Bs[k][tn + 32 * j];
#pragma unroll
            for (int i = 0; i < 8; ++i)
#pragma unroll
                for (int j = 0; j < 8; ++j) acc[i][j] += a[i] * b[j];
        }
        __syncthreads();
    }

#pragma unroll
    for (int i = 0; i < 8; ++i) {
        int row = m0 + tm * 8 + i;
        if (row < n) {
#pragma unroll
            for (int j = 0; j < 8; ++j) {
                int col = tn + 32 * j;
                XLR[(size_t)row * XLR_LD + col] = acc[i][j] + biasp[col];
            }
        }
    }
}

// ---------------------------------------------------------------------------
// Self-loop edge transform: ef_loop[0..95] = mean(ea) @ we_s ; [96..127] = masked mean @ we_r
// ---------------------------------------------------------------------------
__global__ __launch_bounds__(128) void finalize_means(
    const float* __restrict__ sums, const float* __restrict__ we_s,
    const float* __restrict__ we_r, float* __restrict__ ef_loop, int E)
{
    int f = threadIdx.x;
    float v = 0.f;
    if (f < OUT_STD) {
        float inv = 1.f / (float)E;
#pragma unroll
        for (int k = 0; k < 16; ++k) v += sums[k] * inv * we_s[k * OUT_STD + f];
    } else {
        float cnt = sums[32];
        cnt = cnt < 1.f ? 1.f : cnt;
        float inv = 1.f / cnt;
        int c = f - OUT_STD;
#pragma unroll
        for (int k = 0; k < 16; ++k) v += sums[16 + k] * inv * we_r[k * OUT_REP + c];
    }
    ef_loop[f] = v;
}

// ---------------------------------------------------------------------------
// Main fused GATv2: one 128-thread block per node, lane = output feature
// lanes 0..95 = std conv (3 heads x 32), lanes 96..127 = rep conv (1 head)
// ---------------------------------------------------------------------------
__global__ __launch_bounds__(128) void gat_main(
    const float* __restrict__ XLR, const float* __restrict__ ea,
    const int* __restrict__ csr_eid, const int* __restrict__ row_ofs,
    const int* __restrict__ ei, const unsigned char* __restrict__ mask,
    const float* __restrict__ we_s, const float* __restrict__ we_r,
    const float* __restrict__ att_s, const float* __restrict__ att_r,
    const float* __restrict__ bias_s, const float* __restrict__ bias_r,
    const float* __restrict__ ef_loop, float* __restrict__ out, int n)
{
    int node = blockIdx.x;
    int f = threadIdx.x;
    bool is_std = f < OUT_STD;
    int c = f & 31;

    int xl_off = is_std ? f : (96 + f);          // rep: 192 + (f-96)
    int xr_off = is_std ? (96 + f) : (128 + f);  // rep: 224 + (f-96)

    float wecol[16];
    if (is_std) {
#pragma unroll
        for (int k = 0; k < 16; ++k) wecol[k] = we_s[k * OUT_STD + f];
    } else {
#pragma unroll
        for (int k = 0; k < 16; ++k) wecol[k] = we_r[k * OUT_REP + (f - OUT_STD)];
    }
    float attv  = is_std ? att_s[(f >> 5) * 32 + c] : att_r[c];
    float biasv = is_std ? bias_s[f] : bias_r[f - OUT_STD];

    const float* xrow = XLR + (size_t)node * XLR_LD;
    float xr_n = xrow[xr_off];
    float xl_n = xrow[xl_off];

    // self-loop: init online softmax state
    float msg = xl_n + xr_n + ef_loop[f];
    float s = (msg > 0.f ? msg : NEG_SLOPE * msg) * attv;
#pragma unroll
    for (int o = 16; o; o >>= 1) s += __shfl_xor(s, o, 32);
    float m = s, denom = 1.f, acc = xl_n;

    int p0 = row_ofs[node], p1 = row_ofs[node + 1];
    for (int p = p0; p < p1; ++p) {
        int e = csr_eid[p];
        int src = ei[e];
        bool act = is_std || (mask[e] != 0);

        const float4* eap = (const float4*)(ea + (size_t)e * 16);
        float4 e0 = eap[0], e1 = eap[1], e2 = eap[2], e3 = eap[3];
        float ef = e0.x * wecol[0] + e0.y * wecol[1] + e0.z * wecol[2] + e0.w * wecol[3]
                 + e1.x * wecol[4] + e1.y * wecol[5] + e1.z * wecol[6] + e1.w * wecol[7]
                 + e2.x * wecol[8] + e2.y * wecol[9] + e2.z * wecol[10] + e2.w * wecol[11]
                 + e3.x * wecol[12] + e3.y * wecol[13] + e3.z * wecol[14] + e3.w * wecol[15];

        float xls = XLR[(size_t)src * XLR_LD + xl_off];
        float mg = xls + xr_n + ef;
        float sc = (mg > 0.f ? mg : NEG_SLOPE * mg) * attv;
#pragma unroll
        for (int o = 16; o; o >>= 1) sc += __shfl_xor(sc, o, 32);

        if (act) {  // uniform within each 32-lane head group
            if (sc > m) {
                float r = __expf(m - sc);
                denom = denom * r + 1.f;
                acc = acc * r + xls;
                m = sc;
            } else {
                float p2 = __expf(sc - m);
                denom += p2;
                acc += p2 * xls;
            }
        }
    }
    out[(size_t)node * OUT_ALL + f] = acc / denom + biasv;
}

// ---------------------------------------------------------------------------
extern "C" void kernel_launch(void* const* d_in, const int* in_sizes, int n_in,
                              void* d_out, int out_size, void* d_ws, size_t ws_size,
                              hipStream_t stream)
{
    const float* x    = (const float*)d_in[0];
    const float* raw  = (const float*)d_in[1];
    const int*   ei   = (const int*)d_in[2];
    const void*  mask_raw = d_in[3];
    const float* ee_w1 = (const float*)d_in[4];
    const float* ee_b1 = (const float*)d_in[5];
    const float* ee_w2 = (const float*)d_in[6];
    const float* ee_b2 = (const float*)d_in[7];
    const float* wl_s = (const float*)d_in[8];
    const float* bl_s = (const float*)d_in[9];
    const float* wr_s = (const float*)d_in[10];
    const float* br_s = (const float*)d_in[11];
    const float* we_s = (const float*)d_in[12];
    const float* att_s = (const float*)d_in[13];
    const float* bias_s = (const float*)d_in[14];
    const float* wl_r = (const float*)d_in[15];
    const float* bl_r = (const float*)d_in[16];
    const float* wr_r = (const float*)d_in[17];
    const float* br_r = (const float*)d_in[18];
    const float* we_r = (const float*)d_in[19];
    const float* att_r = (const float*)d_in[20];
    const float* bias_r = (const float*)d_in[21];

    const int N = in_sizes[0] / IN_DIM;
    const int E = in_sizes[1] / 7;

    // workspace carve-up (all offsets 256B-aligned)
    char* w = (char*)d_ws;
    size_t off = 0;
    auto carve = [&](size_t bytes) {
        void* p = w + off;
        off = (off + bytes + 255) & ~(size_t)255;
        return p;
    };
    float* XLR     = (float*)carve((size_t)N * XLR_LD * 4);
    float* ea      = (float*)carve((size_t)E * 16 * 4);
    int*   csr_eid = (int*)carve((size_t)E * 4);
    unsigned char* mk8 = (unsigned char*)carve((size_t)E);
    int*   row_ofs = (int*)carve((size_t)(N + 1) * 4);
    int*   cursor  = (int*)carve((size_t)N * 4);
    int*   deg     = (int*)carve((size_t)N * 4);
    int*   part    = (int*)carve(1024);
    float* sums    = (float*)carve(256);
    float* ef_loop = (float*)carve(512);
    float* Wp      = (float*)carve((size_t)IN_DIM * XLR_LD * 4);
    float* biasp   = (float*)carve(1024);
    int*   mflag   = (int*)carve(256);
    (void)ws_size; (void)n_in; (void)out_size;

    hipMemsetAsync(deg, 0, (size_t)N * 4, stream);
    hipMemsetAsync(sums, 0, 256, stream);

    int ebl = (E + 255) / 256;
    int nbl = (N + 255) / 256;

    int nprobe = E < 4096 ? E : 4096;
    mask_detect<<<1, 64, 0, stream>>>((const unsigned char*)mask_raw, mflag, nprobe);
    mask_convert<<<ebl, 256, 0, stream>>>(mask_raw, mflag, mk8, E);

    int eebl = ebl < EE_BLOCKS ? ebl : EE_BLOCKS;
    edge_enc<<<eebl, 256, 0, stream>>>(raw, ei, mk8, ee_w1, ee_b1, ee_w2, ee_b2, ea, deg, sums, E);
    scan1<<<nbl, 256, 0, stream>>>(deg, part, N);
    scan2<<<1, 256, 0, stream>>>(part, nbl);
    scan3<<<nbl, 256, 0, stream>>>(deg, part, row_ofs, cursor, N, E);
    csr_fill<<<ebl, 256, 0, stream>>>(ei, cursor, csr_eid, E);
    pack_w<<<(IN_DIM * XLR_LD + 255) / 256, 256, 0, stream>>>(
        wl_s, wr_s, wl_r, wr_r, bl_s, br_s, bl_r, br_r, Wp, biasp);
    node_gemm<<<(N + GM_BM - 1) / GM_BM, 256, 0, stream>>>(x, Wp, biasp, XLR, N);
    finalize_means<<<1, 128, 0, stream>>>(sums, we_s, we_r, ef_loop, E);
    gat_main<<<N, 128, 0, stream>>>(XLR, ea, csr_eid, row_ofs, ei, mk8,
                                    we_s, we_r, att_s, att_r, bias_s, bias_r,
                                    ef_loop, (float*)d_out, N);
}

// Round 4
// 452.671 us; speedup vs baseline: 7.5089x; 1.1011x over previous
//
#include <hip/hip_runtime.h>
#include <hip/hip_bf16.h>
#include <cstdint>

#define IN_DIM 128
#define OUT_STD 96
#define OUT_REP 32
#define OUT_ALL 128
#define NEG_SLOPE 0.2f
#define EE_BLOCKS 512

// ---------------------------------------------------------------------------
// Mask dtype detection (JAX bool may arrive as uint8 / int32 / f32).
// ---------------------------------------------------------------------------
__global__ void mask_detect(const unsigned char* __restrict__ m, int* __restrict__ flag, int nbytes)
{
    int t = threadIdx.x;
    int anyGT1 = 0, any123 = 0;
    for (int i = t; i < nbytes; i += 64) {
        unsigned char b = m[i];
        if (b > 1) anyGT1 = 1;
        if ((i & 3) && b) any123 = 1;
    }
    anyGT1 = __any(anyGT1);
    any123 = __any(any123);
    if (t == 0) *flag = anyGT1 ? 2 : (any123 ? 0 : 1);
}

__device__ __forceinline__ bool mask_at(const void* m, int fl, int e)
{
    if (fl == 1) return ((const int*)m)[e] != 0;
    if (fl == 2) return ((const float*)m)[e] != 0.f;
    return ((const unsigned char*)m)[e] != 0;
}

// ---------------------------------------------------------------------------
// Edge encoder MLP 7->32->16 (+ deg histogram, + sums). Grid-stride, register
// accumulation, one atomicAdd per block per value.
// sums: [0..15] sum(ea), [16..31] sum(ea*mask), [32] sum(mask)
// ---------------------------------------------------------------------------
__global__ __launch_bounds__(256) void edge_enc(
    const float* __restrict__ raw, const int* __restrict__ ei,
    const void* __restrict__ mraw, const int* __restrict__ mflag,
    const float* __restrict__ w1, const float* __restrict__ b1,
    const float* __restrict__ w2, const float* __restrict__ b2,
    float* __restrict__ ea, int* __restrict__ deg, float* __restrict__ sums, int E)
{
    __shared__ float sW1[7 * 32];
    __shared__ float sB1[32];
    __shared__ float sW2[32 * 16];
    __shared__ float sB2[16];
    __shared__ float red[33][4];
    int t = threadIdx.x;
    if (t < 224) sW1[t] = w1[t];
    if (t < 32)  sB1[t] = b1[t];
    for (int i = t; i < 512; i += 256) sW2[i] = w2[i];
    if (t < 16)  sB2[t] = b2[t];
    __syncthreads();
    int fl = *mflag;

    float accs[16], accm[16], cnt = 0.f;
#pragma unroll
    for (int j = 0; j < 16; ++j) { accs[j] = 0.f; accm[j] = 0.f; }

    for (int e = blockIdx.x * 256 + t; e < E; e += gridDim.x * 256) {
        float r[7];
#pragma unroll
        for (int k = 0; k < 7; ++k) r[k] = raw[(size_t)e * 7 + k];
        float o[16];
#pragma unroll
        for (int j = 0; j < 16; ++j) o[j] = sB2[j];
#pragma unroll
        for (int jh = 0; jh < 32; ++jh) {
            float hv = sB1[jh];
#pragma unroll
            for (int k = 0; k < 7; ++k) hv += r[k] * sW1[k * 32 + jh];
            hv = hv > 0.f ? hv : 0.f;
#pragma unroll
            for (int j = 0; j < 16; ++j) o[j] += hv * sW2[jh * 16 + j];
        }
        float4* dst = (float4*)(ea + (size_t)e * 16);
        dst[0] = make_float4(o[0], o[1], o[2], o[3]);
        dst[1] = make_float4(o[4], o[5], o[6], o[7]);
        dst[2] = make_float4(o[8], o[9], o[10], o[11]);
        dst[3] = make_float4(o[12], o[13], o[14], o[15]);
        atomicAdd(&deg[ei[E + e]], 1);
        float mk = mask_at(mraw, fl, e) ? 1.f : 0.f;
#pragma unroll
        for (int j = 0; j < 16; ++j) { accs[j] += o[j]; accm[j] += o[j] * mk; }
        cnt += mk;
    }

    int wv = t >> 6, ln = t & 63;
#pragma unroll
    for (int j = 0; j < 16; ++j) {
        float v = accs[j], vm = accm[j];
#pragma unroll
        for (int off = 32; off; off >>= 1) {
            v  += __shfl_xor(v, off, 64);
            vm += __shfl_xor(vm, off, 64);
        }
        if (ln == 0) { red[j][wv] = v; red[16 + j][wv] = vm; }
    }
    {
        float c = cnt;
#pragma unroll
        for (int off = 32; off; off >>= 1) c += __shfl_xor(c, off, 64);
        if (ln == 0) red[32][wv] = c;
    }
    __syncthreads();
    if (t < 33) {
        float v = red[t][0] + red[t][1] + red[t][2] + red[t][3];
        atomicAdd(&sums[t], v);
    }
}

// ---------------------------------------------------------------------------
// CSR build
// ---------------------------------------------------------------------------
__global__ __launch_bounds__(256) void scan1(const int* __restrict__ deg, int* __restrict__ part, int n)
{
    __shared__ int sm[256];
    int i = blockIdx.x * 256 + threadIdx.x;
    sm[threadIdx.x] = (i < n) ? deg[i] : 0;
    __syncthreads();
    for (int s = 128; s; s >>= 1) {
        if (threadIdx.x < s) sm[threadIdx.x] += sm[threadIdx.x + s];
        __syncthreads();
    }
    if (threadIdx.x == 0) part[blockIdx.x] = sm[0];
}

__global__ __launch_bounds__(256) void scan2(int* __restrict__ part, int nb)
{
    __shared__ int sm[256];
    int t = threadIdx.x;
    int v = (t < nb) ? part[t] : 0;
    sm[t] = v;
    __syncthreads();
    for (int o = 1; o < 256; o <<= 1) {
        int add = (t >= o) ? sm[t - o] : 0;
        __syncthreads();
        sm[t] += add;
        __syncthreads();
    }
    if (t < nb) part[t] = sm[t] - v;  // exclusive
}

__global__ __launch_bounds__(256) void scan3(const int* __restrict__ deg, const int* __restrict__ part,
                                             int* __restrict__ row_ofs, int* __restrict__ cursor,
                                             int n, int E)
{
    __shared__ int sm[256];
    int t = threadIdx.x;
    int i = blockIdx.x * 256 + t;
    int v = (i < n) ? deg[i] : 0;
    sm[t] = v;
    __syncthreads();
    for (int o = 1; o < 256; o <<= 1) {
        int add = (t >= o) ? sm[t - o] : 0;
        __syncthreads();
        sm[t] += add;
        __syncthreads();
    }
    int excl = sm[t] - v + part[blockIdx.x];
    if (i < n) { row_ofs[i] = excl; cursor[i] = excl; }
    if (blockIdx.x == 0 && t == 0) row_ofs[n] = E;
}

// mask bit packed into csr value bit 31
__global__ __launch_bounds__(256) void csr_fill(const int* __restrict__ ei, int* __restrict__ cursor,
                                                const void* __restrict__ mraw, const int* __restrict__ mflag,
                                                unsigned int* __restrict__ csr_eid, int E)
{
    int e = blockIdx.x * 256 + threadIdx.x;
    if (e < E) {
        int fl = *mflag;
        int d = ei[E + e];
        int slot = atomicAdd(&cursor[d], 1);
        unsigned int v = (unsigned int)e;
        if (mask_at(mraw, fl, e)) v |= 0x80000000u;
        csr_eid[slot] = v;
    }
}

// ---------------------------------------------------------------------------
// Pack weights: Wp[128][256], cols [0,96)=wl_s | [96,128)=wl_r | [128,224)=wr_s | [224,256)=wr_r
// ---------------------------------------------------------------------------
__global__ __launch_bounds__(256) void pack_w(
    const float* __restrict__ wls, const float* __restrict__ wrs,
    const float* __restrict__ wlr, const float* __restrict__ wrr,
    const float* __restrict__ bls, const float* __restrict__ brs,
    const float* __restrict__ blr, const float* __restrict__ brr,
    float* __restrict__ Wp, float* __restrict__ biasp)
{
    int idx = blockIdx.x * 256 + threadIdx.x;
    if (idx < IN_DIM * 256) {
        int k = idx >> 8, j = idx & 255;
        float v;
        if (j < 96)       v = wls[k * 96 + j];
        else if (j < 128) v = wlr[k * 32 + (j - 96)];
        else if (j < 224) v = wrs[k * 96 + (j - 128)];
        else              v = wrr[k * 32 + (j - 224)];
        Wp[idx] = v;
    }
    if (idx < 256) {
        float b;
        if (idx < 96)       b = bls[idx];
        else if (idx < 128) b = blr[idx - 96];
        else if (idx < 224) b = brs[idx - 128];
        else                b = brr[idx - 224];
        biasp[idx] = b;
    }
}

// ---------------------------------------------------------------------------
// Node transforms -> XL[N][128] (src side, gathered) and XR[N][128] (dst side)
// ---------------------------------------------------------------------------
#define GM_BM 64
#define GM_BK 16
__global__ __launch_bounds__(256) void node_gemm(
    const float* __restrict__ x, const float* __restrict__ Wp,
    const float* __restrict__ biasp, float* __restrict__ XL,
    float* __restrict__ XR, int n)
{
    __shared__ __align__(16) float As[GM_BK][GM_BM];
    __shared__ __align__(16) float Bs[GM_BK][256];
    int tid = threadIdx.x;
    int tm = tid >> 5;   // 0..7
    int tn = tid & 31;   // 0..31
    int m0 = blockIdx.x * GM_BM;
    float acc[8][8] = {{0.f}};

    for (int k0 = 0; k0 < IN_DIM; k0 += GM_BK) {
        {
            int r = tid >> 2, c0 = (tid & 3) * 4;
            float4 av = make_float4(0.f, 0.f, 0.f, 0.f);
            if (m0 + r < n) av = *(const float4*)(x + (size_t)(m0 + r) * IN_DIM + k0 + c0);
            As[c0 + 0][r] = av.x; As[c0 + 1][r] = av.y;
            As[c0 + 2][r] = av.z; As[c0 + 3][r] = av.w;
        }
        {
            int rb = tid >> 4, cb0 = (tid & 15) * 16;
            const float4* src = (const float4*)(Wp + (size_t)(k0 + rb) * 256 + cb0);
            float4 b0 = src[0], b1 = src[1], b2 = src[2], b3 = src[3];
            *(float4*)&Bs[rb][cb0 + 0]  = b0; *(float4*)&Bs[rb][cb0 + 4]  = b1;
            *(float4*)&Bs[rb][cb0 + 8]  = b2; *(float4*)&Bs[rb][cb0 + 12] = b3;
        }
        __syncthreads();
#pragma unroll
        for (int k = 0; k < GM_BK; ++k) {
            float a[8], b[8];
            *(float4*)&a[0] = *(const float4*)&As[k][tm * 8];
            *(float4*)&a[4] = *(const float4*)&As[k][tm * 8 + 4];
#pragma unroll
            for (int j = 0; j < 8; ++j) b[j] = Bs[k][tn + 32 * j];
#pragma unroll
            for (int i = 0; i < 8; ++i)
#pragma unroll
                for (int j = 0; j < 8; ++j) acc[i][j] += a[i] * b[j];
        }
        __syncthreads();
    }

#pragma unroll
    for (int i = 0; i < 8; ++i) {
        int row = m0 + tm * 8 + i;
        if (row < n) {
#pragma unroll
            for (int j = 0; j < 4; ++j) {
                int col = tn + 32 * j;
                XL[(size_t)row * 128 + col] = acc[i][j] + biasp[col];
            }
#pragma unroll
            for (int j = 4; j < 8; ++j) {
                int col = tn + 32 * (j - 4);
                XR[(size_t)row * 128 + col] = acc[i][j] + biasp[128 + col];
            }
        }
    }
}

// ---------------------------------------------------------------------------
// Fused GATv2: one 128-thread block per node, lane = output feature.
// 4-way edge unroll + batched online softmax. Self-loop ef computed inline.
// ---------------------------------------------------------------------------
__global__ __launch_bounds__(128) void gat_main(
    const float* __restrict__ XL, const float* __restrict__ XR,
    const float* __restrict__ ea, const unsigned int* __restrict__ csr_eid,
    const int* __restrict__ row_ofs, const int* __restrict__ ei,
    const float* __restrict__ sums,
    const float* __restrict__ we_s, const float* __restrict__ we_r,
    const float* __restrict__ att_s, const float* __restrict__ att_r,
    const float* __restrict__ bias_s, const float* __restrict__ bias_r,
    float* __restrict__ out, int n, int E)
{
    int node = blockIdx.x;
    int f = threadIdx.x;
    bool is_std = f < OUT_STD;

    float wecol[16];
    if (is_std) {
#pragma unroll
        for (int k = 0; k < 16; ++k) wecol[k] = we_s[k * OUT_STD + f];
    } else {
#pragma unroll
        for (int k = 0; k < 16; ++k) wecol[k] = we_r[k * OUT_REP + (f - OUT_STD)];
    }
    float attv  = is_std ? att_s[f] : att_r[f - OUT_STD];
    float biasv = is_std ? bias_s[f] : bias_r[f - OUT_STD];

    float xl_n = XL[(size_t)node * 128 + f];
    float xr_n = XR[(size_t)node * 128 + f];

    // self-loop edge feature (mean / masked-mean through we), inline
    float efl = 0.f;
    {
        float c = sums[32]; c = c < 1.f ? 1.f : c;
        float scl = is_std ? (1.f / (float)E) : (1.f / c);
        const float* sp = is_std ? sums : (sums + 16);
#pragma unroll
        for (int k = 0; k < 16; ++k) efl += sp[k] * scl * wecol[k];
    }

    float msg = xl_n + xr_n + efl;
    float s = fmaxf(msg, NEG_SLOPE * msg) * attv;
#pragma unroll
    for (int o = 16; o; o >>= 1) s += __shfl_xor(s, o, 32);
    float m = s, denom = 1.f, acc = xl_n;

    int p0 = row_ofs[node], p1 = row_ofs[node + 1];
    for (int p = p0; p < p1; p += 4) {
        float sc[4], xls[4];
        bool act[4];
#pragma unroll
        for (int i = 0; i < 4; ++i) {
            int pp = p + i;
            bool valid = pp < p1;
            if (!valid) pp = p1 - 1;
            unsigned int pk = csr_eid[pp];
            int e = __builtin_amdgcn_readfirstlane((int)(pk & 0x7fffffffu));
            bool mbit = (pk & 0x80000000u) != 0;
            act[i] = valid && (is_std || mbit);
            int src = __builtin_amdgcn_readfirstlane(ei[e]);
            xls[i] = XL[(size_t)src * 128 + f];
            const float* ear = ea + (size_t)e * 16;
            float efv = 0.f;
#pragma unroll
            for (int k = 0; k < 16; ++k) efv += ear[k] * wecol[k];
            float mg = xls[i] + xr_n + efv;
            sc[i] = fmaxf(mg, NEG_SLOPE * mg) * attv;
        }
#pragma unroll
        for (int o = 16; o; o >>= 1) {
#pragma unroll
            for (int i = 0; i < 4; ++i) sc[i] += __shfl_xor(sc[i], o, 32);
        }
#pragma unroll
        for (int i = 0; i < 4; ++i) if (!act[i]) sc[i] = -INFINITY;

        float mn = fmaxf(fmaxf(fmaxf(sc[0], sc[1]), fmaxf(sc[2], sc[3])), m);
        float r  = __expf(m - mn);
        float q0 = __expf(sc[0] - mn), q1 = __expf(sc[1] - mn);
        float q2 = __expf(sc[2] - mn), q3 = __expf(sc[3] - mn);
        denom = denom * r + ((q0 + q1) + (q2 + q3));
        acc   = acc * r + ((q0 * xls[0] + q1 * xls[1]) + (q2 * xls[2] + q3 * xls[3]));
        m = mn;
    }
    out[(size_t)node * OUT_ALL + f] = acc / denom + biasv;
}

// ---------------------------------------------------------------------------
extern "C" void kernel_launch(void* const* d_in, const int* in_sizes, int n_in,
                              void* d_out, int out_size, void* d_ws, size_t ws_size,
                              hipStream_t stream)
{
    const float* x    = (const float*)d_in[0];
    const float* raw  = (const float*)d_in[1];
    const int*   ei   = (const int*)d_in[2];
    const void*  mask_raw = d_in[3];
    const float* ee_w1 = (const float*)d_in[4];
    const float* ee_b1 = (const float*)d_in[5];
    const float* ee_w2 = (const float*)d_in[6];
    const float* ee_b2 = (const float*)d_in[7];
    const float* wl_s = (const float*)d_in[8];
    const float* bl_s = (const float*)d_in[9];
    const float* wr_s = (const float*)d_in[10];
    const float* br_s = (const float*)d_in[11];
    const float* we_s = (const float*)d_in[12];
    const float* att_s = (const float*)d_in[13];
    const float* bias_s = (const float*)d_in[14];
    const float* wl_r = (const float*)d_in[15];
    const float* bl_r = (const float*)d_in[16];
    const float* wr_r = (const float*)d_in[17];
    const float* br_r = (const float*)d_in[18];
    const float* we_r = (const float*)d_in[19];
    const float* att_r = (const float*)d_in[20];
    const float* bias_r = (const float*)d_in[21];

    const int N = in_sizes[0] / IN_DIM;
    const int E = in_sizes[1] / 7;

    char* w = (char*)d_ws;
    size_t off = 0;
    auto carve = [&](size_t bytes) {
        void* p = w + off;
        off = (off + bytes + 255) & ~(size_t)255;
        return p;
    };
    float* XL      = (float*)carve((size_t)N * 128 * 4);
    float* XR      = (float*)carve((size_t)N * 128 * 4);
    float* ea      = (float*)carve((size_t)E * 16 * 4);
    unsigned int* csr_eid = (unsigned int*)carve((size_t)E * 4);
    int*   row_ofs = (int*)carve((size_t)(N + 1) * 4);
    int*   cursor  = (int*)carve((size_t)N * 4);
    int*   deg     = (int*)carve((size_t)N * 4);
    int*   part    = (int*)carve(1024);
    float* sums    = (float*)carve(256);
    float* Wp      = (float*)carve((size_t)IN_DIM * 256 * 4);
    float* biasp   = (float*)carve(1024);
    int*   mflag   = (int*)carve(256);
    (void)ws_size; (void)n_in; (void)out_size;

    hipMemsetAsync(deg, 0, (size_t)N * 4, stream);
    hipMemsetAsync(sums, 0, 256, stream);

    int ebl = (E + 255) / 256;
    int nbl = (N + 255) / 256;

    int nprobe = E < 4096 ? E : 4096;
    mask_detect<<<1, 64, 0, stream>>>((const unsigned char*)mask_raw, mflag, nprobe);

    int eebl = ebl < EE_BLOCKS ? ebl : EE_BLOCKS;
    edge_enc<<<eebl, 256, 0, stream>>>(raw, ei, mask_raw, mflag, ee_w1, ee_b1, ee_w2, ee_b2, ea, deg, sums, E);
    scan1<<<nbl, 256, 0, stream>>>(deg, part, N);
    scan2<<<1, 256, 0, stream>>>(part, nbl);
    scan3<<<nbl, 256, 0, stream>>>(deg, part, row_ofs, cursor, N, E);
    csr_fill<<<ebl, 256, 0, stream>>>(ei, cursor, mask_raw, mflag, csr_eid, E);
    pack_w<<<(IN_DIM * 256 + 255) / 256, 256, 0, stream>>>(
        wl_s, wr_s, wl_r, wr_r, bl_s, br_s, bl_r, br_r, Wp, biasp);
    node_gemm<<<(N + GM_BM - 1) / GM_BM, 256, 0, stream>>>(x, Wp, biasp, XL, XR, N);
    gat_main<<<N, 128, 0, stream>>>(XL, XR, ea, csr_eid, row_ofs, ei, sums,
                                    we_s, we_r, att_s, att_r, bias_s, bias_r,
                                    (float*)d_out, N, E);
}

// Round 5
// 425.687 us; speedup vs baseline: 7.9849x; 1.0634x over previous
//
#include <hip/hip_runtime.h>
#include <hip/hip_bf16.h>
#include <cstdint>

#define IN_DIM 128
#define OUT_STD 96
#define OUT_REP 32
#define OUT_ALL 128
#define NEG_SLOPE 0.2f
#define EE_BLOCKS 512

typedef _Float16 h2 __attribute__((ext_vector_type(2)));

// ---------------------------------------------------------------------------
// Mask dtype detection (JAX bool may arrive as uint8 / int32 / f32).
// ---------------------------------------------------------------------------
__global__ void mask_detect(const unsigned char* __restrict__ m, int* __restrict__ flag, int nbytes)
{
    int t = threadIdx.x;
    int anyGT1 = 0, any123 = 0;
    for (int i = t; i < nbytes; i += 64) {
        unsigned char b = m[i];
        if (b > 1) anyGT1 = 1;
        if ((i & 3) && b) any123 = 1;
    }
    anyGT1 = __any(anyGT1);
    any123 = __any(any123);
    if (t == 0) *flag = anyGT1 ? 2 : (any123 ? 0 : 1);
}

__device__ __forceinline__ bool mask_at(const void* m, int fl, int e)
{
    if (fl == 1) return ((const int*)m)[e] != 0;
    if (fl == 2) return ((const float*)m)[e] != 0.f;
    return ((const unsigned char*)m)[e] != 0;
}

// ---------------------------------------------------------------------------
// Edge encoder MLP 7->32->16 (+ deg histogram, + sums). Grid-stride, register
// accumulation, one atomicAdd per block per value. ea written as f16.
// sums: [0..15] sum(ea), [16..31] sum(ea*mask), [32] sum(mask)
// ---------------------------------------------------------------------------
__global__ __launch_bounds__(256) void edge_enc(
    const float* __restrict__ raw, const int* __restrict__ ei,
    const void* __restrict__ mraw, const int* __restrict__ mflag,
    const float* __restrict__ w1, const float* __restrict__ b1,
    const float* __restrict__ w2, const float* __restrict__ b2,
    _Float16* __restrict__ ea, int* __restrict__ deg, float* __restrict__ sums, int E)
{
    __shared__ float sW1[7 * 32];
    __shared__ float sB1[32];
    __shared__ float sW2[32 * 16];
    __shared__ float sB2[16];
    __shared__ float red[33][4];
    int t = threadIdx.x;
    if (t < 224) sW1[t] = w1[t];
    if (t < 32)  sB1[t] = b1[t];
    for (int i = t; i < 512; i += 256) sW2[i] = w2[i];
    if (t < 16)  sB2[t] = b2[t];
    __syncthreads();
    int fl = *mflag;

    float accs[16], accm[16], cnt = 0.f;
#pragma unroll
    for (int j = 0; j < 16; ++j) { accs[j] = 0.f; accm[j] = 0.f; }

    for (int e = blockIdx.x * 256 + t; e < E; e += gridDim.x * 256) {
        float r[7];
#pragma unroll
        for (int k = 0; k < 7; ++k) r[k] = raw[(size_t)e * 7 + k];
        float o[16];
#pragma unroll
        for (int j = 0; j < 16; ++j) o[j] = sB2[j];
#pragma unroll
        for (int jh = 0; jh < 32; ++jh) {
            float hv = sB1[jh];
#pragma unroll
            for (int k = 0; k < 7; ++k) hv += r[k] * sW1[k * 32 + jh];
            hv = hv > 0.f ? hv : 0.f;
#pragma unroll
            for (int j = 0; j < 16; ++j) o[j] += hv * sW2[jh * 16 + j];
        }
        union { h2 h[8]; uint4 u[2]; } pk;
#pragma unroll
        for (int j = 0; j < 8; ++j) pk.h[j] = h2{(_Float16)o[2 * j], (_Float16)o[2 * j + 1]};
        uint4* dst = (uint4*)(ea + (size_t)e * 16);
        dst[0] = pk.u[0];
        dst[1] = pk.u[1];
        atomicAdd(&deg[ei[E + e]], 1);
        float mk = mask_at(mraw, fl, e) ? 1.f : 0.f;
#pragma unroll
        for (int j = 0; j < 16; ++j) { accs[j] += o[j]; accm[j] += o[j] * mk; }
        cnt += mk;
    }

    int wv = t >> 6, ln = t & 63;
#pragma unroll
    for (int j = 0; j < 16; ++j) {
        float v = accs[j], vm = accm[j];
#pragma unroll
        for (int off = 32; off; off >>= 1) {
            v  += __shfl_xor(v, off, 64);
            vm += __shfl_xor(vm, off, 64);
        }
        if (ln == 0) { red[j][wv] = v; red[16 + j][wv] = vm; }
    }
    {
        float c = cnt;
#pragma unroll
        for (int off = 32; off; off >>= 1) c += __shfl_xor(c, off, 64);
        if (ln == 0) red[32][wv] = c;
    }
    __syncthreads();
    if (t < 33) {
        float v = red[t][0] + red[t][1] + red[t][2] + red[t][3];
        atomicAdd(&sums[t], v);
    }
}

// ---------------------------------------------------------------------------
// CSR build
// ---------------------------------------------------------------------------
__global__ __launch_bounds__(256) void scan1(const int* __restrict__ deg, int* __restrict__ part, int n)
{
    __shared__ int sm[256];
    int i = blockIdx.x * 256 + threadIdx.x;
    sm[threadIdx.x] = (i < n) ? deg[i] : 0;
    __syncthreads();
    for (int s = 128; s; s >>= 1) {
        if (threadIdx.x < s) sm[threadIdx.x] += sm[threadIdx.x + s];
        __syncthreads();
    }
    if (threadIdx.x == 0) part[blockIdx.x] = sm[0];
}

__global__ __launch_bounds__(256) void scan2(int* __restrict__ part, int nb)
{
    __shared__ int sm[256];
    int t = threadIdx.x;
    int v = (t < nb) ? part[t] : 0;
    sm[t] = v;
    __syncthreads();
    for (int o = 1; o < 256; o <<= 1) {
        int add = (t >= o) ? sm[t - o] : 0;
        __syncthreads();
        sm[t] += add;
        __syncthreads();
    }
    if (t < nb) part[t] = sm[t] - v;  // exclusive
}

__global__ __launch_bounds__(256) void scan3(const int* __restrict__ deg, const int* __restrict__ part,
                                             int* __restrict__ row_ofs, int* __restrict__ cursor,
                                             int n, int E)
{
    __shared__ int sm[256];
    int t = threadIdx.x;
    int i = blockIdx.x * 256 + t;
    int v = (i < n) ? deg[i] : 0;
    sm[t] = v;
    __syncthreads();
    for (int o = 1; o < 256; o <<= 1) {
        int add = (t >= o) ? sm[t - o] : 0;
        __syncthreads();
        sm[t] += add;
        __syncthreads();
    }
    int excl = sm[t] - v + part[blockIdx.x];
    if (i < n) { row_ofs[i] = excl; cursor[i] = excl; }
    if (blockIdx.x == 0 && t == 0) row_ofs[n] = E;
}

// mask bit packed into csr value bit 31
__global__ __launch_bounds__(256) void csr_fill(const int* __restrict__ ei, int* __restrict__ cursor,
                                                const void* __restrict__ mraw, const int* __restrict__ mflag,
                                                unsigned int* __restrict__ csr_eid, int E)
{
    int e = blockIdx.x * 256 + threadIdx.x;
    if (e < E) {
        int fl = *mflag;
        int d = ei[E + e];
        int slot = atomicAdd(&cursor[d], 1);
        unsigned int v = (unsigned int)e;
        if (mask_at(mraw, fl, e)) v |= 0x80000000u;
        csr_eid[slot] = v;
    }
}

// ---------------------------------------------------------------------------
// Node transforms (pack fused): XL[N][128] f16 (gathered side), XR[N][128] f32.
// Virtual B cols: [0,96)=wl_s | [96,128)=wl_r | [128,224)=wr_s | [224,256)=wr_r
// 16-col staging segments never cross the 96/128/224 boundaries.
// ---------------------------------------------------------------------------
#define GM_BM 64
#define GM_BK 16
__global__ __launch_bounds__(256) void node_gemm(
    const float* __restrict__ x,
    const float* __restrict__ wls, const float* __restrict__ wrs,
    const float* __restrict__ wlr, const float* __restrict__ wrr,
    const float* __restrict__ bls, const float* __restrict__ brs,
    const float* __restrict__ blr, const float* __restrict__ brr,
    _Float16* __restrict__ XLh, float* __restrict__ XR, int n)
{
    __shared__ __align__(16) float As[GM_BK][GM_BM];
    __shared__ __align__(16) float Bs[GM_BK][256];
    int tid = threadIdx.x;
    int tm = tid >> 5;   // 0..7
    int tn = tid & 31;   // 0..31
    int m0 = blockIdx.x * GM_BM;
    float acc[8][8] = {{0.f}};

    // B source select for this thread's 16-col staging segment
    int rb = tid >> 4, cb0 = (tid & 15) * 16;
    const float* bsp; int bld, bc0;
    if (cb0 < 96)       { bsp = wls; bld = 96; bc0 = cb0; }
    else if (cb0 < 128) { bsp = wlr; bld = 32; bc0 = cb0 - 96; }
    else if (cb0 < 224) { bsp = wrs; bld = 96; bc0 = cb0 - 128; }
    else                { bsp = wrr; bld = 32; bc0 = cb0 - 224; }

    for (int k0 = 0; k0 < IN_DIM; k0 += GM_BK) {
        {
            int r = tid >> 2, c0 = (tid & 3) * 4;
            float4 av = make_float4(0.f, 0.f, 0.f, 0.f);
            if (m0 + r < n) av = *(const float4*)(x + (size_t)(m0 + r) * IN_DIM + k0 + c0);
            As[c0 + 0][r] = av.x; As[c0 + 1][r] = av.y;
            As[c0 + 2][r] = av.z; As[c0 + 3][r] = av.w;
        }
        {
            const float4* src = (const float4*)(bsp + (size_t)(k0 + rb) * bld + bc0);
            float4 b0 = src[0], b1 = src[1], b2 = src[2], b3 = src[3];
            *(float4*)&Bs[rb][cb0 + 0]  = b0; *(float4*)&Bs[rb][cb0 + 4]  = b1;
            *(float4*)&Bs[rb][cb0 + 8]  = b2; *(float4*)&Bs[rb][cb0 + 12] = b3;
        }
        __syncthreads();
#pragma unroll
        for (int k = 0; k < GM_BK; ++k) {
            float a[8], b[8];
            *(float4*)&a[0] = *(const float4*)&As[k][tm * 8];
            *(float4*)&a[4] = *(const float4*)&As[k][tm * 8 + 4];
#pragma unroll
            for (int j = 0; j < 8; ++j) b[j] = Bs[k][tn + 32 * j];
#pragma unroll
            for (int i = 0; i < 8; ++i)
#pragma unroll
                for (int j = 0; j < 8; ++j) acc[i][j] += a[i] * b[j];
        }
        __syncthreads();
    }

#pragma unroll
    for (int i = 0; i < 8; ++i) {
        int row = m0 + tm * 8 + i;
        if (row < n) {
#pragma unroll
            for (int j = 0; j < 4; ++j) {
                int col = tn + 32 * j;   // in [0,128): XL side
                float b = col < 96 ? bls[col] : blr[col - 96];
                XLh[(size_t)row * 128 + col] = (_Float16)(acc[i][j] + b);
            }
#pragma unroll
            for (int j = 4; j < 8; ++j) {
                int c = tn + 32 * (j - 4);  // in [0,128): XR side
                float b = c < 96 ? brs[c] : brr[c - 96];
                XR[(size_t)row * 128 + c] = acc[i][j] + b;
            }
        }
    }
}

// ---------------------------------------------------------------------------
// Fused GATv2: one 128-thread block per node, lane = output feature.
// 4-way edge unroll + batched online softmax. f16 gathers + v_dot2_f32_f16.
// ---------------------------------------------------------------------------
__global__ __launch_bounds__(128) void gat_main(
    const _Float16* __restrict__ XLh, const float* __restrict__ XR,
    const _Float16* __restrict__ ea, const unsigned int* __restrict__ csr_eid,
    const int* __restrict__ row_ofs, const int* __restrict__ ei,
    const float* __restrict__ sums,
    const float* __restrict__ we_s, const float* __restrict__ we_r,
    const float* __restrict__ att_s, const float* __restrict__ att_r,
    const float* __restrict__ bias_s, const float* __restrict__ bias_r,
    float* __restrict__ out, int n, int E)
{
    int node = blockIdx.x;
    int f = threadIdx.x;
    bool is_std = f < OUT_STD;

    float wef[16];
    if (is_std) {
#pragma unroll
        for (int k = 0; k < 16; ++k) wef[k] = we_s[k * OUT_STD + f];
    } else {
#pragma unroll
        for (int k = 0; k < 16; ++k) wef[k] = we_r[k * OUT_REP + (f - OUT_STD)];
    }
    h2 wech[8];
#pragma unroll
    for (int k = 0; k < 8; ++k) wech[k] = h2{(_Float16)wef[2 * k], (_Float16)wef[2 * k + 1]};

    float attv  = is_std ? att_s[f] : att_r[f - OUT_STD];
    float biasv = is_std ? bias_s[f] : bias_r[f - OUT_STD];

    float xl_n = (float)XLh[(size_t)node * 128 + f];
    float xr_n = XR[(size_t)node * 128 + f];

    // self-loop edge feature (mean / masked-mean through we), inline
    float efl = 0.f;
    {
        float c = sums[32]; c = c < 1.f ? 1.f : c;
        float scl = is_std ? (1.f / (float)E) : (1.f / c);
        const float* sp = is_std ? sums : (sums + 16);
#pragma unroll
        for (int k = 0; k < 16; ++k) efl += sp[k] * scl * wef[k];
    }

    float msg = xl_n + xr_n + efl;
    float s = fmaxf(msg, NEG_SLOPE * msg) * attv;
#pragma unroll
    for (int o = 16; o; o >>= 1) s += __shfl_xor(s, o, 32);
    float m = s, denom = 1.f, acc = xl_n;

    int p0 = row_ofs[node], p1 = row_ofs[node + 1];
    for (int p = p0; p < p1; p += 4) {
        float sc[4], xls[4];
        bool act[4];
#pragma unroll
        for (int i = 0; i < 4; ++i) {
            int pp = p + i;
            bool valid = pp < p1;
            if (!valid) pp = p1 - 1;
            unsigned int pk = csr_eid[pp];
            int e = __builtin_amdgcn_readfirstlane((int)(pk & 0x7fffffffu));
            bool mbit = (pk & 0x80000000u) != 0;
            act[i] = valid && (is_std || mbit);
            int src = __builtin_amdgcn_readfirstlane(ei[e]);
            xls[i] = (float)XLh[(size_t)src * 128 + f];
            union { uint4 u[2]; h2 h[8]; } pe;
            const uint4* eap = (const uint4*)(ea + (size_t)e * 16);
            pe.u[0] = eap[0]; pe.u[1] = eap[1];
            float efv = 0.f;
#pragma unroll
            for (int k = 0; k < 8; ++k)
                efv = __builtin_amdgcn_fdot2(pe.h[k], wech[k], efv, false);
            float mg = xls[i] + xr_n + efv;
            sc[i] = fmaxf(mg, NEG_SLOPE * mg) * attv;
        }
#pragma unroll
        for (int o = 16; o; o >>= 1) {
#pragma unroll
            for (int i = 0; i < 4; ++i) sc[i] += __shfl_xor(sc[i], o, 32);
        }
#pragma unroll
        for (int i = 0; i < 4; ++i) if (!act[i]) sc[i] = -INFINITY;

        float mn = fmaxf(fmaxf(fmaxf(sc[0], sc[1]), fmaxf(sc[2], sc[3])), m);
        float r  = __expf(m - mn);
        float q0 = __expf(sc[0] - mn), q1 = __expf(sc[1] - mn);
        float q2 = __expf(sc[2] - mn), q3 = __expf(sc[3] - mn);
        denom = denom * r + ((q0 + q1) + (q2 + q3));
        acc   = acc * r + ((q0 * xls[0] + q1 * xls[1]) + (q2 * xls[2] + q3 * xls[3]));
        m = mn;
    }
    out[(size_t)node * OUT_ALL + f] = acc / denom + biasv;
}

// ---------------------------------------------------------------------------
extern "C" void kernel_launch(void* const* d_in, const int* in_sizes, int n_in,
                              void* d_out, int out_size, void* d_ws, size_t ws_size,
                              hipStream_t stream)
{
    const float* x    = (const float*)d_in[0];
    const float* raw  = (const float*)d_in[1];
    const int*   ei   = (const int*)d_in[2];
    const void*  mask_raw = d_in[3];
    const float* ee_w1 = (const float*)d_in[4];
    const float* ee_b1 = (const float*)d_in[5];
    const float* ee_w2 = (const float*)d_in[6];
    const float* ee_b2 = (const float*)d_in[7];
    const float* wl_s = (const float*)d_in[8];
    const float* bl_s = (const float*)d_in[9];
    const float* wr_s = (const float*)d_in[10];
    const float* br_s = (const float*)d_in[11];
    const float* we_s = (const float*)d_in[12];
    const float* att_s = (const float*)d_in[13];
    const float* bias_s = (const float*)d_in[14];
    const float* wl_r = (const float*)d_in[15];
    const float* bl_r = (const float*)d_in[16];
    const float* wr_r = (const float*)d_in[17];
    const float* br_r = (const float*)d_in[18];
    const float* we_r = (const float*)d_in[19];
    const float* att_r = (const float*)d_in[20];
    const float* bias_r = (const float*)d_in[21];

    const int N = in_sizes[0] / IN_DIM;
    const int E = in_sizes[1] / 7;

    char* w = (char*)d_ws;
    size_t off = 0;
    auto carve = [&](size_t bytes) {
        void* p = w + off;
        off = (off + bytes + 255) & ~(size_t)255;
        return p;
    };
    _Float16* XLh  = (_Float16*)carve((size_t)N * 128 * 2);
    float* XR      = (float*)carve((size_t)N * 128 * 4);
    _Float16* ea   = (_Float16*)carve((size_t)E * 16 * 2);
    unsigned int* csr_eid = (unsigned int*)carve((size_t)E * 4);
    int*   row_ofs = (int*)carve((size_t)(N + 1) * 4);
    int*   cursor  = (int*)carve((size_t)N * 4);
    int*   deg     = (int*)carve((size_t)N * 4);
    int*   part    = (int*)carve(1024);
    float* sums    = (float*)carve(256);
    int*   mflag   = (int*)carve(256);
    (void)ws_size; (void)n_in; (void)out_size;

    hipMemsetAsync(deg, 0, (size_t)N * 4, stream);
    hipMemsetAsync(sums, 0, 256, stream);

    int ebl = (E + 255) / 256;
    int nbl = (N + 255) / 256;

    int nprobe = E < 4096 ? E : 4096;
    mask_detect<<<1, 64, 0, stream>>>((const unsigned char*)mask_raw, mflag, nprobe);

    int eebl = ebl < EE_BLOCKS ? ebl : EE_BLOCKS;
    edge_enc<<<eebl, 256, 0, stream>>>(raw, ei, mask_raw, mflag, ee_w1, ee_b1, ee_w2, ee_b2, ea, deg, sums, E);
    scan1<<<nbl, 256, 0, stream>>>(deg, part, N);
    scan2<<<1, 256, 0, stream>>>(part, nbl);
    scan3<<<nbl, 256, 0, stream>>>(deg, part, row_ofs, cursor, N, E);
    csr_fill<<<ebl, 256, 0, stream>>>(ei, cursor, mask_raw, mflag, csr_eid, E);
    node_gemm<<<(N + GM_BM - 1) / GM_BM, 256, 0, stream>>>(
        x, wl_s, wr_s, wl_r, wr_r, bl_s, br_s, bl_r, br_r, XLh, XR, N);
    gat_main<<<N, 128, 0, stream>>>(XLh, XR, ea, csr_eid, row_ofs, ei, sums,
                                    we_s, we_r, att_s, att_r, bias_s, bias_r,
                                    (float*)d_out, N, E);
}

// Round 7
// 425.394 us; speedup vs baseline: 7.9904x; 1.0007x over previous
//
#include <hip/hip_runtime.h>
#include <hip/hip_bf16.h>
#include <cstdint>

#define IN_DIM 128
#define OUT_STD 96
#define OUT_REP 32
#define OUT_ALL 128
#define NEG_SLOPE 0.2f
#define EE_BLOCKS 512
#define LOG2E 1.4426950408889634f

typedef _Float16 h2 __attribute__((ext_vector_type(2)));

// 32-lane group sum: 4 DPP stages (VALU) + one cross-16 shuffle.
// ctrl must be a compile-time constant -> template parameter.
template <int CTRL>
__device__ __forceinline__ float dpp_add(float v)
{
    int x = __builtin_amdgcn_update_dpp(0, __float_as_int(v), CTRL, 0xf, 0xf, true);
    return v + __int_as_float(x);
}
__device__ __forceinline__ float grp32_sum(float v)
{
    v = dpp_add<0xB1>(v);   // quad_perm [1,0,3,2]  (xor 1)
    v = dpp_add<0x4E>(v);   // quad_perm [2,3,0,1]  (xor 2)
    v = dpp_add<0x141>(v);  // row_half_mirror      (xor 4-equiv)
    v = dpp_add<0x140>(v);  // row_mirror           (xor 8-equiv)
    v += __shfl_xor(v, 16, 32);
    return v;
}

// ---------------------------------------------------------------------------
// Mask dtype detection (JAX bool may arrive as uint8 / int32 / f32).
// ---------------------------------------------------------------------------
__global__ void mask_detect(const unsigned char* __restrict__ m, int* __restrict__ flag, int nbytes)
{
    int t = threadIdx.x;
    int anyGT1 = 0, any123 = 0;
    for (int i = t; i < nbytes; i += 64) {
        unsigned char b = m[i];
        if (b > 1) anyGT1 = 1;
        if ((i & 3) && b) any123 = 1;
    }
    anyGT1 = __any(anyGT1);
    any123 = __any(any123);
    if (t == 0) *flag = anyGT1 ? 2 : (any123 ? 0 : 1);
}

__device__ __forceinline__ bool mask_at(const void* m, int fl, int e)
{
    if (fl == 1) return ((const int*)m)[e] != 0;
    if (fl == 2) return ((const float*)m)[e] != 0.f;
    return ((const unsigned char*)m)[e] != 0;
}

// ---------------------------------------------------------------------------
// Edge encoder MLP 7->32->16 (+ deg histogram, + sums). Grid-stride, register
// accumulation, one atomicAdd per block per value. ea written as f16.
// sums: [0..15] sum(ea), [16..31] sum(ea*mask), [32] sum(mask)
// ---------------------------------------------------------------------------
__global__ __launch_bounds__(256) void edge_enc(
    const float* __restrict__ raw, const int* __restrict__ ei,
    const void* __restrict__ mraw, const int* __restrict__ mflag,
    const float* __restrict__ w1, const float* __restrict__ b1,
    const float* __restrict__ w2, const float* __restrict__ b2,
    _Float16* __restrict__ ea, int* __restrict__ deg, float* __restrict__ sums, int E)
{
    __shared__ float sW1[7 * 32];
    __shared__ float sB1[32];
    __shared__ float sW2[32 * 16];
    __shared__ float sB2[16];
    __shared__ float red[33][4];
    int t = threadIdx.x;
    if (t < 224) sW1[t] = w1[t];
    if (t < 32)  sB1[t] = b1[t];
    for (int i = t; i < 512; i += 256) sW2[i] = w2[i];
    if (t < 16)  sB2[t] = b2[t];
    __syncthreads();
    int fl = *mflag;

    float accs[16], accm[16], cnt = 0.f;
#pragma unroll
    for (int j = 0; j < 16; ++j) { accs[j] = 0.f; accm[j] = 0.f; }

    for (int e = blockIdx.x * 256 + t; e < E; e += gridDim.x * 256) {
        float r[7];
#pragma unroll
        for (int k = 0; k < 7; ++k) r[k] = raw[(size_t)e * 7 + k];
        float o[16];
#pragma unroll
        for (int j = 0; j < 16; ++j) o[j] = sB2[j];
#pragma unroll
        for (int jh = 0; jh < 32; ++jh) {
            float hv = sB1[jh];
#pragma unroll
            for (int k = 0; k < 7; ++k) hv += r[k] * sW1[k * 32 + jh];
            hv = hv > 0.f ? hv : 0.f;
#pragma unroll
            for (int j = 0; j < 16; ++j) o[j] += hv * sW2[jh * 16 + j];
        }
        union { h2 h[8]; uint4 u[2]; } pk;
#pragma unroll
        for (int j = 0; j < 8; ++j) pk.h[j] = h2{(_Float16)o[2 * j], (_Float16)o[2 * j + 1]};
        uint4* dst = (uint4*)(ea + (size_t)e * 16);
        dst[0] = pk.u[0];
        dst[1] = pk.u[1];
        atomicAdd(&deg[ei[E + e]], 1);
        float mk = mask_at(mraw, fl, e) ? 1.f : 0.f;
#pragma unroll
        for (int j = 0; j < 16; ++j) { accs[j] += o[j]; accm[j] += o[j] * mk; }
        cnt += mk;
    }

    int wv = t >> 6, ln = t & 63;
#pragma unroll
    for (int j = 0; j < 16; ++j) {
        float v = accs[j], vm = accm[j];
#pragma unroll
        for (int off = 32; off; off >>= 1) {
            v  += __shfl_xor(v, off, 64);
            vm += __shfl_xor(vm, off, 64);
        }
        if (ln == 0) { red[j][wv] = v; red[16 + j][wv] = vm; }
    }
    {
        float c = cnt;
#pragma unroll
        for (int off = 32; off; off >>= 1) c += __shfl_xor(c, off, 64);
        if (ln == 0) red[32][wv] = c;
    }
    __syncthreads();
    if (t < 33) {
        float v = red[t][0] + red[t][1] + red[t][2] + red[t][3];
        atomicAdd(&sums[t], v);
    }
}

// ---------------------------------------------------------------------------
// CSR build
// ---------------------------------------------------------------------------
__global__ __launch_bounds__(256) void scan1(const int* __restrict__ deg, int* __restrict__ part, int n)
{
    __shared__ int sm[256];
    int i = blockIdx.x * 256 + threadIdx.x;
    sm[threadIdx.x] = (i < n) ? deg[i] : 0;
    __syncthreads();
    for (int s = 128; s; s >>= 1) {
        if (threadIdx.x < s) sm[threadIdx.x] += sm[threadIdx.x + s];
        __syncthreads();
    }
    if (threadIdx.x == 0) part[blockIdx.x] = sm[0];
}

__global__ __launch_bounds__(256) void scan2(int* __restrict__ part, int nb)
{
    __shared__ int sm[256];
    int t = threadIdx.x;
    int v = (t < nb) ? part[t] : 0;
    sm[t] = v;
    __syncthreads();
    for (int o = 1; o < 256; o <<= 1) {
        int add = (t >= o) ? sm[t - o] : 0;
        __syncthreads();
        sm[t] += add;
        __syncthreads();
    }
    if (t < nb) part[t] = sm[t] - v;  // exclusive
}

__global__ __launch_bounds__(256) void scan3(const int* __restrict__ deg, const int* __restrict__ part,
                                             int* __restrict__ row_ofs, int* __restrict__ cursor,
                                             int n, int E)
{
    __shared__ int sm[256];
    int t = threadIdx.x;
    int i = blockIdx.x * 256 + t;
    int v = (i < n) ? deg[i] : 0;
    sm[t] = v;
    __syncthreads();
    for (int o = 1; o < 256; o <<= 1) {
        int add = (t >= o) ? sm[t - o] : 0;
        __syncthreads();
        sm[t] += add;
        __syncthreads();
    }
    int excl = sm[t] - v + part[blockIdx.x];
    if (i < n) { row_ofs[i] = excl; cursor[i] = excl; }
    if (blockIdx.x == 0 && t == 0) row_ofs[n] = E;
}

// mask bit packed into csr value bit 31
__global__ __launch_bounds__(256) void csr_fill(const int* __restrict__ ei, int* __restrict__ cursor,
                                                const void* __restrict__ mraw, const int* __restrict__ mflag,
                                                unsigned int* __restrict__ csr_eid, int E)
{
    int e = blockIdx.x * 256 + threadIdx.x;
    if (e < E) {
        int fl = *mflag;
        int d = ei[E + e];
        int slot = atomicAdd(&cursor[d], 1);
        unsigned int v = (unsigned int)e;
        if (mask_at(mraw, fl, e)) v |= 0x80000000u;
        csr_eid[slot] = v;
    }
}

// ---------------------------------------------------------------------------
// Node transforms (pack fused): XL[N][128] f16 (gathered side), XR[N][128] f32.
// Virtual B cols: [0,96)=wl_s | [96,128)=wl_r | [128,224)=wr_s | [224,256)=wr_r
// ---------------------------------------------------------------------------
#define GM_BM 64
#define GM_BK 16
__global__ __launch_bounds__(256) void node_gemm(
    const float* __restrict__ x,
    const float* __restrict__ wls, const float* __restrict__ wrs,
    const float* __restrict__ wlr, const float* __restrict__ wrr,
    const float* __restrict__ bls, const float* __restrict__ brs,
    const float* __restrict__ blr, const float* __restrict__ brr,
    _Float16* __restrict__ XLh, float* __restrict__ XR, int n)
{
    __shared__ __align__(16) float As[GM_BK][GM_BM];
    __shared__ __align__(16) float Bs[GM_BK][256];
    int tid = threadIdx.x;
    int tm = tid >> 5;   // 0..7
    int tn = tid & 31;   // 0..31
    int m0 = blockIdx.x * GM_BM;
    float acc[8][8] = {{0.f}};

    int rb = tid >> 4, cb0 = (tid & 15) * 16;
    const float* bsp; int bld, bc0;
    if (cb0 < 96)       { bsp = wls; bld = 96; bc0 = cb0; }
    else if (cb0 < 128) { bsp = wlr; bld = 32; bc0 = cb0 - 96; }
    else if (cb0 < 224) { bsp = wrs; bld = 96; bc0 = cb0 - 128; }
    else                { bsp = wrr; bld = 32; bc0 = cb0 - 224; }

    for (int k0 = 0; k0 < IN_DIM; k0 += GM_BK) {
        {
            int r = tid >> 2, c0 = (tid & 3) * 4;
            float4 av = make_float4(0.f, 0.f, 0.f, 0.f);
            if (m0 + r < n) av = *(const float4*)(x + (size_t)(m0 + r) * IN_DIM + k0 + c0);
            As[c0 + 0][r] = av.x; As[c0 + 1][r] = av.y;
            As[c0 + 2][r] = av.z; As[c0 + 3][r] = av.w;
        }
        {
            const float4* src = (const float4*)(bsp + (size_t)(k0 + rb) * bld + bc0);
            float4 b0 = src[0], b1 = src[1], b2 = src[2], b3 = src[3];
            *(float4*)&Bs[rb][cb0 + 0]  = b0; *(float4*)&Bs[rb][cb0 + 4]  = b1;
            *(float4*)&Bs[rb][cb0 + 8]  = b2; *(float4*)&Bs[rb][cb0 + 12] = b3;
        }
        __syncthreads();
#pragma unroll
        for (int k = 0; k < GM_BK; ++k) {
            float a[8], b[8];
            *(float4*)&a[0] = *(const float4*)&As[k][tm * 8];
            *(float4*)&a[4] = *(const float4*)&As[k][tm * 8 + 4];
#pragma unroll
            for (int j = 0; j < 8; ++j) b[j] = Bs[k][tn + 32 * j];
#pragma unroll
            for (int i = 0; i < 8; ++i)
#pragma unroll
                for (int j = 0; j < 8; ++j) acc[i][j] += a[i] * b[j];
        }
        __syncthreads();
    }

#pragma unroll
    for (int i = 0; i < 8; ++i) {
        int row = m0 + tm * 8 + i;
        if (row < n) {
#pragma unroll
            for (int j = 0; j < 4; ++j) {
                int col = tn + 32 * j;
                float b = col < 96 ? bls[col] : blr[col - 96];
                XLh[(size_t)row * 128 + col] = (_Float16)(acc[i][j] + b);
            }
#pragma unroll
            for (int j = 4; j < 8; ++j) {
                int c = tn + 32 * (j - 4);
                float b = c < 96 ? brs[c] : brr[c - 96];
                XR[(size_t)row * 128 + c] = acc[i][j] + b;
            }
        }
    }
}

// ---------------------------------------------------------------------------
// Fused GATv2: one 128-thread block per node, lane = output feature.
// 8-way edge unroll, DPP group reduce, exp2-domain online softmax.
// ---------------------------------------------------------------------------
__global__ __launch_bounds__(128) void gat_main(
    const _Float16* __restrict__ XLh, const float* __restrict__ XR,
    const _Float16* __restrict__ ea, const unsigned int* __restrict__ csr_eid,
    const int* __restrict__ row_ofs, const int* __restrict__ ei,
    const float* __restrict__ sums,
    const float* __restrict__ we_s, const float* __restrict__ we_r,
    const float* __restrict__ att_s, const float* __restrict__ att_r,
    const float* __restrict__ bias_s, const float* __restrict__ bias_r,
    float* __restrict__ out, int n, int E)
{
    int node = blockIdx.x;
    int f = threadIdx.x;
    bool is_std = f < OUT_STD;

    float wef[16];
    if (is_std) {
#pragma unroll
        for (int k = 0; k < 16; ++k) wef[k] = we_s[k * OUT_STD + f];
    } else {
#pragma unroll
        for (int k = 0; k < 16; ++k) wef[k] = we_r[k * OUT_REP + (f - OUT_STD)];
    }
    h2 wech[8];
#pragma unroll
    for (int k = 0; k < 8; ++k) wech[k] = h2{(_Float16)wef[2 * k], (_Float16)wef[2 * k + 1]};

    // log2-domain attention vector: exp(s) == exp2(s*log2e)
    float attv  = (is_std ? att_s[f] : att_r[f - OUT_STD]) * LOG2E;
    float biasv = is_std ? bias_s[f] : bias_r[f - OUT_STD];

    float xl_n = (float)XLh[(size_t)node * 128 + f];
    float xr_n = XR[(size_t)node * 128 + f];

    // self-loop edge feature (mean / masked-mean through we), inline
    float efl = 0.f;
    {
        float c = sums[32]; c = c < 1.f ? 1.f : c;
        float scl = is_std ? (1.f / (float)E) : (1.f / c);
        const float* sp = is_std ? sums : (sums + 16);
#pragma unroll
        for (int k = 0; k < 16; ++k) efl += sp[k] * scl * wef[k];
    }

    float msg = xl_n + xr_n + efl;
    float m = grp32_sum(fmaxf(msg, NEG_SLOPE * msg) * attv);
    float denom = 1.f, acc = xl_n;

    int p0 = row_ofs[node], p1 = row_ofs[node + 1];
    for (int p = p0; p < p1; p += 8) {
        float sc[8], xls[8];
#pragma unroll
        for (int i = 0; i < 8; ++i) {
            int pp = p + i;
            bool valid = pp < p1;
            if (!valid) pp = p1 - 1;
            unsigned int pk = csr_eid[pp];
            int e = __builtin_amdgcn_readfirstlane((int)(pk & 0x7fffffffu));
            bool mbit = (pk & 0x80000000u) != 0;
            bool act = valid && (is_std || mbit);
            int src = __builtin_amdgcn_readfirstlane(ei[e]);
            xls[i] = (float)XLh[(size_t)src * 128 + f];
            union { uint4 u[2]; h2 h[8]; } pe;
            const uint4* eap = (const uint4*)(ea + (size_t)e * 16);
            pe.u[0] = eap[0]; pe.u[1] = eap[1];
            float efv = 0.f;
#pragma unroll
            for (int k = 0; k < 8; ++k)
                efv = __builtin_amdgcn_fdot2(pe.h[k], wech[k], efv, false);
            float mg = xls[i] + xr_n + efv;
            float sv = grp32_sum(fmaxf(mg, NEG_SLOPE * mg) * attv);
            sc[i] = act ? sv : -INFINITY;
        }

        float mn = m;
#pragma unroll
        for (int i = 0; i < 8; ++i) mn = fmaxf(mn, sc[i]);
        float r = exp2f(m - mn);
        float q[8];
#pragma unroll
        for (int i = 0; i < 8; ++i) q[i] = exp2f(sc[i] - mn);
        float qs = ((q[0] + q[1]) + (q[2] + q[3])) + ((q[4] + q[5]) + (q[6] + q[7]));
        denom = denom * r + qs;
        float xa = ((q[0] * xls[0] + q[1] * xls[1]) + (q[2] * xls[2] + q[3] * xls[3]))
                 + ((q[4] * xls[4] + q[5] * xls[5]) + (q[6] * xls[6] + q[7] * xls[7]));
        acc = acc * r + xa;
        m = mn;
    }
    out[(size_t)node * OUT_ALL + f] = acc / denom + biasv;
}

// ---------------------------------------------------------------------------
extern "C" void kernel_launch(void* const* d_in, const int* in_sizes, int n_in,
                              void* d_out, int out_size, void* d_ws, size_t ws_size,
                              hipStream_t stream)
{
    const float* x    = (const float*)d_in[0];
    const float* raw  = (const float*)d_in[1];
    const int*   ei   = (const int*)d_in[2];
    const void*  mask_raw = d_in[3];
    const float* ee_w1 = (const float*)d_in[4];
    const float* ee_b1 = (const float*)d_in[5];
    const float* ee_w2 = (const float*)d_in[6];
    const float* ee_b2 = (const float*)d_in[7];
    const float* wl_s = (const float*)d_in[8];
    const float* bl_s = (const float*)d_in[9];
    const float* wr_s = (const float*)d_in[10];
    const float* br_s = (const float*)d_in[11];
    const float* we_s = (const float*)d_in[12];
    const float* att_s = (const float*)d_in[13];
    const float* bias_s = (const float*)d_in[14];
    const float* wl_r = (const float*)d_in[15];
    const float* bl_r = (const float*)d_in[16];
    const float* wr_r = (const float*)d_in[17];
    const float* br_r = (const float*)d_in[18];
    const float* we_r = (const float*)d_in[19];
    const float* att_r = (const float*)d_in[20];
    const float* bias_r = (const float*)d_in[21];

    const int N = in_sizes[0] / IN_DIM;
    const int E = in_sizes[1] / 7;

    char* w = (char*)d_ws;
    size_t off = 0;
    auto carve = [&](size_t bytes) {
        void* p = w + off;
        off = (off + bytes + 255) & ~(size_t)255;
        return p;
    };
    _Float16* XLh  = (_Float16*)carve((size_t)N * 128 * 2);
    float* XR      = (float*)carve((size_t)N * 128 * 4);
    _Float16* ea   = (_Float16*)carve((size_t)E * 16 * 2);
    unsigned int* csr_eid = (unsigned int*)carve((size_t)E * 4);
    int*   row_ofs = (int*)carve((size_t)(N + 1) * 4);
    int*   cursor  = (int*)carve((size_t)N * 4);
    int*   deg     = (int*)carve((size_t)N * 4);
    int*   part    = (int*)carve(1024);
    float* sums    = (float*)carve(256);
    int*   mflag   = (int*)carve(256);
    (void)ws_size; (void)n_in; (void)out_size;

    hipMemsetAsync(deg, 0, (size_t)N * 4, stream);
    hipMemsetAsync(sums, 0, 256, stream);

    int ebl = (E + 255) / 256;
    int nbl = (N + 255) / 256;

    int nprobe = E < 4096 ? E : 4096;
    mask_detect<<<1, 64, 0, stream>>>((const unsigned char*)mask_raw, mflag, nprobe);

    int eebl = ebl < EE_BLOCKS ? ebl : EE_BLOCKS;
    edge_enc<<<eebl, 256, 0, stream>>>(raw, ei, mask_raw, mflag, ee_w1, ee_b1, ee_w2, ee_b2, ea, deg, sums, E);
    scan1<<<nbl, 256, 0, stream>>>(deg, part, N);
    scan2<<<1, 256, 0, stream>>>(part, nbl);
    scan3<<<nbl, 256, 0, stream>>>(deg, part, row_ofs, cursor, N, E);
    csr_fill<<<ebl, 256, 0, stream>>>(ei, cursor, mask_raw, mflag, csr_eid, E);
    node_gemm<<<(N + GM_BM - 1) / GM_BM, 256, 0, stream>>>(
        x, wl_s, wr_s, wl_r, wr_r, bl_s, br_s, bl_r, br_r, XLh, XR, N);
    gat_main<<<N, 128, 0, stream>>>(XLh, XR, ea, csr_eid, row_ofs, ei, sums,
                                    we_s, we_r, att_s, att_r, bias_s, bias_r,
                                    (float*)d_out, N, E);
}

// Round 8
// 355.338 us; speedup vs baseline: 9.5657x; 1.1972x over previous
//
#include <hip/hip_runtime.h>
#include <hip/hip_bf16.h>
#include <cstdint>

#define IN_DIM 128
#define OUT_STD 96
#define OUT_REP 32
#define OUT_ALL 128
#define NEG_SLOPE 0.2f
#define EE_BLOCKS 512
#define LOG2E 1.4426950408889634f

typedef _Float16 h2 __attribute__((ext_vector_type(2)));

// 32-lane group sum: 4 DPP stages (VALU) + one xor-16 ds_swizzle.
template <int CTRL>
__device__ __forceinline__ float dpp_add(float v)
{
    int x = __builtin_amdgcn_update_dpp(0, __float_as_int(v), CTRL, 0xf, 0xf, true);
    return v + __int_as_float(x);
}
__device__ __forceinline__ float grp32_sum(float v)
{
    v = dpp_add<0xB1>(v);   // quad_perm xor1
    v = dpp_add<0x4E>(v);   // quad_perm xor2
    v = dpp_add<0x141>(v);  // row_half_mirror (xor4)
    v = dpp_add<0x140>(v);  // row_mirror (xor8)
    int x = __builtin_amdgcn_ds_swizzle(__float_as_int(v), 0x401F); // xor16 within 32
    return v + __int_as_float(x);
}

// ---------------------------------------------------------------------------
// Mask dtype detection (JAX bool may arrive as uint8 / int32 / f32).
// ---------------------------------------------------------------------------
__global__ void mask_detect(const unsigned char* __restrict__ m, int* __restrict__ flag, int nbytes)
{
    int t = threadIdx.x;
    int anyGT1 = 0, any123 = 0;
    for (int i = t; i < nbytes; i += 64) {
        unsigned char b = m[i];
        if (b > 1) anyGT1 = 1;
        if ((i & 3) && b) any123 = 1;
    }
    anyGT1 = __any(anyGT1);
    any123 = __any(any123);
    if (t == 0) *flag = anyGT1 ? 2 : (any123 ? 0 : 1);
}

__device__ __forceinline__ bool mask_at(const void* m, int fl, int e)
{
    if (fl == 1) return ((const int*)m)[e] != 0;
    if (fl == 2) return ((const float*)m)[e] != 0.f;
    return ((const unsigned char*)m)[e] != 0;
}

// ---------------------------------------------------------------------------
// Edge encoder MLP 7->32->16 (+ deg histogram, + sums). ea written as f16.
// sums: [0..15] sum(ea), [16..31] sum(ea*mask), [32] sum(mask)
// ---------------------------------------------------------------------------
__global__ __launch_bounds__(256) void edge_enc(
    const float* __restrict__ raw, const int* __restrict__ ei,
    const void* __restrict__ mraw, const int* __restrict__ mflag,
    const float* __restrict__ w1, const float* __restrict__ b1,
    const float* __restrict__ w2, const float* __restrict__ b2,
    _Float16* __restrict__ ea, int* __restrict__ deg, float* __restrict__ sums, int E)
{
    __shared__ float sW1[7 * 32];
    __shared__ float sB1[32];
    __shared__ float sW2[32 * 16];
    __shared__ float sB2[16];
    __shared__ float red[33][4];
    int t = threadIdx.x;
    if (t < 224) sW1[t] = w1[t];
    if (t < 32)  sB1[t] = b1[t];
    for (int i = t; i < 512; i += 256) sW2[i] = w2[i];
    if (t < 16)  sB2[t] = b2[t];
    __syncthreads();
    int fl = *mflag;

    float accs[16], accm[16], cnt = 0.f;
#pragma unroll
    for (int j = 0; j < 16; ++j) { accs[j] = 0.f; accm[j] = 0.f; }

    for (int e = blockIdx.x * 256 + t; e < E; e += gridDim.x * 256) {
        float r[7];
#pragma unroll
        for (int k = 0; k < 7; ++k) r[k] = raw[(size_t)e * 7 + k];
        float o[16];
#pragma unroll
        for (int j = 0; j < 16; ++j) o[j] = sB2[j];
#pragma unroll
        for (int jh = 0; jh < 32; ++jh) {
            float hv = sB1[jh];
#pragma unroll
            for (int k = 0; k < 7; ++k) hv += r[k] * sW1[k * 32 + jh];
            hv = hv > 0.f ? hv : 0.f;
#pragma unroll
            for (int j = 0; j < 16; ++j) o[j] += hv * sW2[jh * 16 + j];
        }
        union { h2 h[8]; uint4 u[2]; } pk;
#pragma unroll
        for (int j = 0; j < 8; ++j) pk.h[j] = h2{(_Float16)o[2 * j], (_Float16)o[2 * j + 1]};
        uint4* dst = (uint4*)(ea + (size_t)e * 16);
        dst[0] = pk.u[0];
        dst[1] = pk.u[1];
        atomicAdd(&deg[ei[E + e]], 1);
        float mk = mask_at(mraw, fl, e) ? 1.f : 0.f;
#pragma unroll
        for (int j = 0; j < 16; ++j) { accs[j] += o[j]; accm[j] += o[j] * mk; }
        cnt += mk;
    }

    int wv = t >> 6, ln = t & 63;
#pragma unroll
    for (int j = 0; j < 16; ++j) {
        float v = accs[j], vm = accm[j];
#pragma unroll
        for (int off = 32; off; off >>= 1) {
            v  += __shfl_xor(v, off, 64);
            vm += __shfl_xor(vm, off, 64);
        }
        if (ln == 0) { red[j][wv] = v; red[16 + j][wv] = vm; }
    }
    {
        float c = cnt;
#pragma unroll
        for (int off = 32; off; off >>= 1) c += __shfl_xor(c, off, 64);
        if (ln == 0) red[32][wv] = c;
    }
    __syncthreads();
    if (t < 33) {
        float v = red[t][0] + red[t][1] + red[t][2] + red[t][3];
        atomicAdd(&sums[t], v);
    }
}

// ---------------------------------------------------------------------------
// CSR build
// ---------------------------------------------------------------------------
__global__ __launch_bounds__(256) void scan1(const int* __restrict__ deg, int* __restrict__ part, int n)
{
    __shared__ int sm[256];
    int i = blockIdx.x * 256 + threadIdx.x;
    sm[threadIdx.x] = (i < n) ? deg[i] : 0;
    __syncthreads();
    for (int s = 128; s; s >>= 1) {
        if (threadIdx.x < s) sm[threadIdx.x] += sm[threadIdx.x + s];
        __syncthreads();
    }
    if (threadIdx.x == 0) part[blockIdx.x] = sm[0];
}

__global__ __launch_bounds__(256) void scan2(int* __restrict__ part, int nb)
{
    __shared__ int sm[256];
    int t = threadIdx.x;
    int v = (t < nb) ? part[t] : 0;
    sm[t] = v;
    __syncthreads();
    for (int o = 1; o < 256; o <<= 1) {
        int add = (t >= o) ? sm[t - o] : 0;
        __syncthreads();
        sm[t] += add;
        __syncthreads();
    }
    if (t < nb) part[t] = sm[t] - v;  // exclusive
}

__global__ __launch_bounds__(256) void scan3(const int* __restrict__ deg, const int* __restrict__ part,
                                             int* __restrict__ row_ofs, int* __restrict__ cursor,
                                             int n, int E)
{
    __shared__ int sm[256];
    int t = threadIdx.x;
    int i = blockIdx.x * 256 + t;
    int v = (i < n) ? deg[i] : 0;
    sm[t] = v;
    __syncthreads();
    for (int o = 1; o < 256; o <<= 1) {
        int add = (t >= o) ? sm[t - o] : 0;
        __syncthreads();
        sm[t] += add;
        __syncthreads();
    }
    int excl = sm[t] - v + part[blockIdx.x];
    if (i < n) { row_ofs[i] = excl; cursor[i] = excl; }
    if (blockIdx.x == 0 && t == 0) row_ofs[n] = E;
}

// csr entry: {e | maskbit<<31, src}
__global__ __launch_bounds__(256) void csr_fill(const int* __restrict__ ei, int* __restrict__ cursor,
                                                const void* __restrict__ mraw, const int* __restrict__ mflag,
                                                uint2* __restrict__ csr, int E)
{
    int e = blockIdx.x * 256 + threadIdx.x;
    if (e < E) {
        int fl = *mflag;
        int s = ei[e];
        int d = ei[E + e];
        int slot = atomicAdd(&cursor[d], 1);
        unsigned int v = (unsigned int)e;
        if (mask_at(mraw, fl, e)) v |= 0x80000000u;
        csr[slot] = make_uint2(v, (unsigned int)s);
    }
}

// ---------------------------------------------------------------------------
// Node transforms (pack fused): XL[N][128] f16 (gathered side), XR[N][128] f32.
// Virtual B cols: [0,96)=wl_s | [96,128)=wl_r | [128,224)=wr_s | [224,256)=wr_r
// ---------------------------------------------------------------------------
#define GM_BM 64
#define GM_BK 16
__global__ __launch_bounds__(256) void node_gemm(
    const float* __restrict__ x,
    const float* __restrict__ wls, const float* __restrict__ wrs,
    const float* __restrict__ wlr, const float* __restrict__ wrr,
    const float* __restrict__ bls, const float* __restrict__ brs,
    const float* __restrict__ blr, const float* __restrict__ brr,
    _Float16* __restrict__ XLh, float* __restrict__ XR, int n)
{
    __shared__ __align__(16) float As[GM_BK][GM_BM];
    __shared__ __align__(16) float Bs[GM_BK][256];
    int tid = threadIdx.x;
    int tm = tid >> 5;   // 0..7
    int tn = tid & 31;   // 0..31
    int m0 = blockIdx.x * GM_BM;
    float acc[8][8] = {{0.f}};

    int rb = tid >> 4, cb0 = (tid & 15) * 16;
    const float* bsp; int bld, bc0;
    if (cb0 < 96)       { bsp = wls; bld = 96; bc0 = cb0; }
    else if (cb0 < 128) { bsp = wlr; bld = 32; bc0 = cb0 - 96; }
    else if (cb0 < 224) { bsp = wrs; bld = 96; bc0 = cb0 - 128; }
    else                { bsp = wrr; bld = 32; bc0 = cb0 - 224; }

    for (int k0 = 0; k0 < IN_DIM; k0 += GM_BK) {
        {
            int r = tid >> 2, c0 = (tid & 3) * 4;
            float4 av = make_float4(0.f, 0.f, 0.f, 0.f);
            if (m0 + r < n) av = *(const float4*)(x + (size_t)(m0 + r) * IN_DIM + k0 + c0);
            As[c0 + 0][r] = av.x; As[c0 + 1][r] = av.y;
            As[c0 + 2][r] = av.z; As[c0 + 3][r] = av.w;
        }
        {
            const float4* src = (const float4*)(bsp + (size_t)(k0 + rb) * bld + bc0);
            float4 b0 = src[0], b1 = src[1], b2 = src[2], b3 = src[3];
            *(float4*)&Bs[rb][cb0 + 0]  = b0; *(float4*)&Bs[rb][cb0 + 4]  = b1;
            *(float4*)&Bs[rb][cb0 + 8]  = b2; *(float4*)&Bs[rb][cb0 + 12] = b3;
        }
        __syncthreads();
#pragma unroll
        for (int k = 0; k < GM_BK; ++k) {
            float a[8], b[8];
            *(float4*)&a[0] = *(const float4*)&As[k][tm * 8];
            *(float4*)&a[4] = *(const float4*)&As[k][tm * 8 + 4];
#pragma unroll
            for (int j = 0; j < 8; ++j) b[j] = Bs[k][tn + 32 * j];
#pragma unroll
            for (int i = 0; i < 8; ++i)
#pragma unroll
                for (int j = 0; j < 8; ++j) acc[i][j] += a[i] * b[j];
        }
        __syncthreads();
    }

#pragma unroll
    for (int i = 0; i < 8; ++i) {
        int row = m0 + tm * 8 + i;
        if (row < n) {
#pragma unroll
            for (int j = 0; j < 4; ++j) {
                int col = tn + 32 * j;
                float b = col < 96 ? bls[col] : blr[col - 96];
                XLh[(size_t)row * 128 + col] = (_Float16)(acc[i][j] + b);
            }
#pragma unroll
            for (int j = 4; j < 8; ++j) {
                int c = tn + 32 * (j - 4);
                float b = c < 96 ? brs[c] : brr[c - 96];
                XR[(size_t)row * 128 + c] = acc[i][j] + b;
            }
        }
    }
}

// ---------------------------------------------------------------------------
// One edge: gather xls, ea-dot, leaky, group-reduce -> score (named scalars).
// ---------------------------------------------------------------------------
__device__ __forceinline__ void edge_sc(
    const _Float16* __restrict__ XLh, const _Float16* __restrict__ ea,
    const uint2* __restrict__ csr, int pp, int f, bool is_std,
    float xr_n, float attv, const h2* wech, float& s, float& x)
{
    uint2 pk = csr[pp];
    int e = __builtin_amdgcn_readfirstlane((int)(pk.x & 0x7fffffffu));
    bool act = is_std || (pk.x & 0x80000000u);
    int src = __builtin_amdgcn_readfirstlane((int)pk.y);
    x = (float)XLh[(size_t)src * 128 + f];
    union { uint4 u[2]; h2 h[8]; } pe;
    const uint4* eap = (const uint4*)(ea + (size_t)e * 16);
    pe.u[0] = eap[0]; pe.u[1] = eap[1];
    float efv = x + xr_n;
#pragma unroll
    for (int k = 0; k < 8; ++k)
        efv = __builtin_amdgcn_fdot2(pe.h[k], wech[k], efv, false);
    float lk = fmaxf(efv, NEG_SLOPE * efv);
    float sv = grp32_sum(lk * attv);
    s = act ? sv : -INFINITY;
}

// ---------------------------------------------------------------------------
// Fused GATv2: one 128-thread block per node, lane = output feature.
// 8-wide straight-line batches (named scalars) + scalar remainder.
// ---------------------------------------------------------------------------
__global__ __launch_bounds__(128) void gat_main(
    const _Float16* __restrict__ XLh, const float* __restrict__ XR,
    const _Float16* __restrict__ ea, const uint2* __restrict__ csr,
    const int* __restrict__ row_ofs,
    const float* __restrict__ sums,
    const float* __restrict__ we_s, const float* __restrict__ we_r,
    const float* __restrict__ att_s, const float* __restrict__ att_r,
    const float* __restrict__ bias_s, const float* __restrict__ bias_r,
    float* __restrict__ out, int n, int E)
{
    int node = blockIdx.x;
    int f = threadIdx.x;
    bool is_std = f < OUT_STD;

    h2 wech[8];
    float efl = 0.f;
    {
        float c = sums[32]; c = c < 1.f ? 1.f : c;
        float scl = is_std ? (1.f / (float)E) : (1.f / c);
        const float* sp = is_std ? sums : (sums + 16);
#pragma unroll
        for (int k = 0; k < 8; ++k) {
            float w0 = is_std ? we_s[(2 * k) * OUT_STD + f]     : we_r[(2 * k) * OUT_REP + (f - OUT_STD)];
            float w1 = is_std ? we_s[(2 * k + 1) * OUT_STD + f] : we_r[(2 * k + 1) * OUT_REP + (f - OUT_STD)];
            wech[k] = h2{(_Float16)w0, (_Float16)w1};
            efl += sp[2 * k] * scl * w0 + sp[2 * k + 1] * scl * w1;
        }
    }

    float attv  = (is_std ? att_s[f] : att_r[f - OUT_STD]) * LOG2E;
    float biasv = is_std ? bias_s[f] : bias_r[f - OUT_STD];

    float xl_n = (float)XLh[(size_t)node * 128 + f];
    float xr_n = XR[(size_t)node * 128 + f];

    float msg = xl_n + xr_n + efl;
    float lk0 = fmaxf(msg, NEG_SLOPE * msg);
    float m = grp32_sum(lk0 * attv);
    float denom = 1.f, acc = xl_n;

    int p0 = row_ofs[node], p1 = row_ofs[node + 1];
    int p = p0;
    for (; p + 8 <= p1; p += 8) {
        float s0, s1, s2, s3, s4, s5, s6, s7;
        float x0, x1, x2, x3, x4, x5, x6, x7;
        edge_sc(XLh, ea, csr, p + 0, f, is_std, xr_n, attv, wech, s0, x0);
        edge_sc(XLh, ea, csr, p + 1, f, is_std, xr_n, attv, wech, s1, x1);
        edge_sc(XLh, ea, csr, p + 2, f, is_std, xr_n, attv, wech, s2, x2);
        edge_sc(XLh, ea, csr, p + 3, f, is_std, xr_n, attv, wech, s3, x3);
        edge_sc(XLh, ea, csr, p + 4, f, is_std, xr_n, attv, wech, s4, x4);
        edge_sc(XLh, ea, csr, p + 5, f, is_std, xr_n, attv, wech, s5, x5);
        edge_sc(XLh, ea, csr, p + 6, f, is_std, xr_n, attv, wech, s6, x6);
        edge_sc(XLh, ea, csr, p + 7, f, is_std, xr_n, attv, wech, s7, x7);

        float mn = fmaxf(m, fmaxf(fmaxf(fmaxf(s0, s1), fmaxf(s2, s3)),
                                  fmaxf(fmaxf(s4, s5), fmaxf(s6, s7))));
        float r  = exp2f(m - mn);
        float q0 = exp2f(s0 - mn), q1 = exp2f(s1 - mn);
        float q2 = exp2f(s2 - mn), q3 = exp2f(s3 - mn);
        float q4 = exp2f(s4 - mn), q5 = exp2f(s5 - mn);
        float q6 = exp2f(s6 - mn), q7 = exp2f(s7 - mn);
        denom = denom * r + (((q0 + q1) + (q2 + q3)) + ((q4 + q5) + (q6 + q7)));
        acc   = acc * r + (((q0 * x0 + q1 * x1) + (q2 * x2 + q3 * x3))
                         + ((q4 * x4 + q5 * x5) + (q6 * x6 + q7 * x7)));
        m = mn;
    }
    for (; p < p1; ++p) {
        float s8, x8;
        edge_sc(XLh, ea, csr, p, f, is_std, xr_n, attv, wech, s8, x8);
        float mn = fmaxf(m, s8);
        float r  = exp2f(m - mn);
        float q  = exp2f(s8 - mn);
        denom = denom * r + q;
        acc   = acc * r + q * x8;
        m = mn;
    }
    out[(size_t)node * OUT_ALL + f] = acc / denom + biasv;
}

// ---------------------------------------------------------------------------
extern "C" void kernel_launch(void* const* d_in, const int* in_sizes, int n_in,
                              void* d_out, int out_size, void* d_ws, size_t ws_size,
                              hipStream_t stream)
{
    const float* x    = (const float*)d_in[0];
    const float* raw  = (const float*)d_in[1];
    const int*   ei   = (const int*)d_in[2];
    const void*  mask_raw = d_in[3];
    const float* ee_w1 = (const float*)d_in[4];
    const float* ee_b1 = (const float*)d_in[5];
    const float* ee_w2 = (const float*)d_in[6];
    const float* ee_b2 = (const float*)d_in[7];
    const float* wl_s = (const float*)d_in[8];
    const float* bl_s = (const float*)d_in[9];
    const float* wr_s = (const float*)d_in[10];
    const float* br_s = (const float*)d_in[11];
    const float* we_s = (const float*)d_in[12];
    const float* att_s = (const float*)d_in[13];
    const float* bias_s = (const float*)d_in[14];
    const float* wl_r = (const float*)d_in[15];
    const float* bl_r = (const float*)d_in[16];
    const float* wr_r = (const float*)d_in[17];
    const float* br_r = (const float*)d_in[18];
    const float* we_r = (const float*)d_in[19];
    const float* att_r = (const float*)d_in[20];
    const float* bias_r = (const float*)d_in[21];

    const int N = in_sizes[0] / IN_DIM;
    const int E = in_sizes[1] / 7;

    char* w = (char*)d_ws;
    size_t off = 0;
    auto carve = [&](size_t bytes) {
        void* p = w + off;
        off = (off + bytes + 255) & ~(size_t)255;
        return p;
    };
    _Float16* XLh  = (_Float16*)carve((size_t)N * 128 * 2);
    float* XR      = (float*)carve((size_t)N * 128 * 4);
    _Float16* ea   = (_Float16*)carve((size_t)E * 16 * 2);
    uint2* csr     = (uint2*)carve((size_t)E * 8);
    int*   row_ofs = (int*)carve((size_t)(N + 1) * 4);
    int*   cursor  = (int*)carve((size_t)N * 4);
    int*   deg     = (int*)carve((size_t)N * 4);
    int*   part    = (int*)carve(1024);
    float* sums    = (float*)carve(256);
    int*   mflag   = (int*)carve(256);
    (void)ws_size; (void)n_in; (void)out_size;

    hipMemsetAsync(deg, 0, (size_t)N * 4, stream);
    hipMemsetAsync(sums, 0, 256, stream);

    int ebl = (E + 255) / 256;
    int nbl = (N + 255) / 256;

    int nprobe = E < 4096 ? E : 4096;
    mask_detect<<<1, 64, 0, stream>>>((const unsigned char*)mask_raw, mflag, nprobe);

    int eebl = ebl < EE_BLOCKS ? ebl : EE_BLOCKS;
    edge_enc<<<eebl, 256, 0, stream>>>(raw, ei, mask_raw, mflag, ee_w1, ee_b1, ee_w2, ee_b2, ea, deg, sums, E);
    scan1<<<nbl, 256, 0, stream>>>(deg, part, N);
    scan2<<<1, 256, 0, stream>>>(part, nbl);
    scan3<<<nbl, 256, 0, stream>>>(deg, part, row_ofs, cursor, N, E);
    csr_fill<<<ebl, 256, 0, stream>>>(ei, cursor, mask_raw, mflag, csr, E);
    node_gemm<<<(N + GM_BM - 1) / GM_BM, 256, 0, stream>>>(
        x, wl_s, wr_s, wl_r, wr_r, bl_s, br_s, bl_r, br_r, XLh, XR, N);
    gat_main<<<N, 128, 0, stream>>>(XLh, XR, ea, csr, row_ofs, sums,
                                    we_s, we_r, att_s, att_r, bias_s, bias_r,
                                    (float*)d_out, N, E);
}